// Round 19
// baseline (167.072 us; speedup 1.0000x reference)
//
#include <hip/hip_runtime.h>
#include <math.h>

#define LOG2E 1.44269504088896340736f

typedef float f32x2 __attribute__((ext_vector_type(2)));
__device__ __forceinline__ f32x2 pkfma(f32x2 a, f32x2 b, f32x2 c) {
    return __builtin_elementwise_fma(a, b, c);
}
__device__ __forceinline__ f32x2 sp(float s) { f32x2 v = {s, s}; return v; }
__device__ __forceinline__ f32x2 lrelu2(f32x2 m) {
    return __builtin_elementwise_max(m, 0.2f * m);
}
// raw v_exp_f32 (single inst); logits/activations are O(1) so denorm path irrelevant
__device__ __forceinline__ float fexp2(float x) {
    float r;
    asm("v_exp_f32 %0, %1" : "=v"(r) : "v"(x));
    return r;
}
// elu via raw exp2: v>0 ? v : e^v-1
__device__ __forceinline__ float elu1(float v) {
    return v > 0.0f ? v : fexp2(v * LOG2E) - 1.0f;
}

// butterfly add via DPP (pure VALU, no LDS): xor1=quad_perm[1,0,3,2],
// xor2=quad_perm[2,3,0,1], 8-lane mirror = row_half_mirror
#define DPPADD(p, ctrl) \
    p += __int_as_float(__builtin_amdgcn_mov_dpp(__float_as_int(p), ctrl, 0xF, 0xF, true))
#define RED8(p) do { DPPADD(p, 0xB1); DPPADD(p, 0x4E); DPPADD(p, 0x141); } while (0)

// ---------------- CSR build: two-level counting sort (no global atomics) ----

__global__ void k_bcnt(const int* __restrict__ dst, int* __restrict__ cntmat,
                       int E, int CE, int NBK) {
    __shared__ int cnt[256];
    int t = threadIdx.x;
    if (t < 256) cnt[t] = 0;
    __syncthreads();
    int c = blockIdx.x;
    int lo = c * CE, hi = min(E, lo + CE);
    int len = hi - lo; if (len < 0) len = 0;
    int len4 = len & ~3;
    for (int o = t * 4; o < len4; o += 4096) {
        int4 d4 = *(const int4*)(dst + lo + o);
        atomicAdd(&cnt[d4.x >> 8], 1);
        atomicAdd(&cnt[d4.y >> 8], 1);
        atomicAdd(&cnt[d4.z >> 8], 1);
        atomicAdd(&cnt[d4.w >> 8], 1);
    }
    for (int o = len4 + t; o < len; o += 1024)
        atomicAdd(&cnt[dst[lo + o] >> 8], 1);
    __syncthreads();
    if (t < NBK) cntmat[t * 256 + c] = cnt[t];
}

__global__ void k_scan1(const int* __restrict__ in, int* __restrict__ out,
                        int* __restrict__ blocksum, int L) {
    __shared__ int sm[256];
    int t = threadIdx.x;
    int i = blockIdx.x * 256 + t;
    int v = (i < L) ? in[i] : 0;
    sm[t] = v;
    __syncthreads();
    #pragma unroll
    for (int off = 1; off < 256; off <<= 1) {
        int add = (t >= off) ? sm[t - off] : 0;
        __syncthreads();
        sm[t] += add;
        __syncthreads();
    }
    if (i < L) out[i] = sm[t] - v;   // exclusive (block-local)
    if (t == 255) blocksum[blockIdx.x] = sm[255];
}

// scan block totals in place; idle threads also build the k-major W2 table:
// Wint[k*8+j] = (Wl2[k][j], Wr2[k][j])  -> 8 j-lanes share one cache line
__global__ void k_scan2(int* __restrict__ blocksum, int nb,
                        const float* __restrict__ Wl2, const float* __restrict__ Wr2,
                        float2* __restrict__ Wint) {
    __shared__ int sm[256];
    int t = threadIdx.x;
    int v = (t < nb) ? blocksum[t] : 0;
    sm[t] = v;
    __syncthreads();
    #pragma unroll
    for (int off = 1; off < 256; off <<= 1) {
        int add = (t >= off) ? sm[t - off] : 0;
        __syncthreads();
        sm[t] += add;
        __syncthreads();
    }
    if (t < nb) blocksum[t] = sm[t] - v;
    #pragma unroll
    for (int i = 0; i < 4; ++i) {
        int idx = t + i * 256;
        Wint[idx] = make_float2(Wl2[idx], Wr2[idx]);
    }
}

__global__ void k_part(const int* __restrict__ src, const int* __restrict__ dst,
                       const float* __restrict__ ea, const int* __restrict__ gofs,
                       const int* __restrict__ blocksum,
                       int2* __restrict__ tmp, int E, int CE, int NBK) {
    __shared__ int cur[256];
    int t = threadIdx.x;
    int c = blockIdx.x;
    if (t < NBK) cur[t] = gofs[t * 256 + c] + blocksum[t];
    __syncthreads();
    int lo = c * CE, hi = min(E, lo + CE);
    int len = hi - lo; if (len < 0) len = 0;
    int len4 = len & ~3;
    for (int o = t * 4; o < len4; o += 4096) {
        int e = lo + o;
        int4 s4 = *(const int4*)(src + e);
        int4 d4 = *(const int4*)(dst + e);
        float4 a4 = *(const float4*)(ea + e);
        int p0 = atomicAdd(&cur[d4.x >> 8], 1);
        int p1 = atomicAdd(&cur[d4.y >> 8], 1);
        int p2 = atomicAdd(&cur[d4.z >> 8], 1);
        int p3 = atomicAdd(&cur[d4.w >> 8], 1);
        tmp[p0] = make_int2(((d4.x & 255) << 24) | (s4.x << 4), __float_as_int(a4.x));
        tmp[p1] = make_int2(((d4.y & 255) << 24) | (s4.y << 4), __float_as_int(a4.y));
        tmp[p2] = make_int2(((d4.z & 255) << 24) | (s4.z << 4), __float_as_int(a4.z));
        tmp[p3] = make_int2(((d4.w & 255) << 24) | (s4.w << 4), __float_as_int(a4.w));
    }
    for (int o = len4 + t; o < len; o += 1024) {
        int e = lo + o;
        int d = dst[e];
        int pos = atomicAdd(&cur[d >> 8], 1);
        tmp[pos] = make_int2(((d & 255) << 24) | (src[e] << 4), __float_as_int(ea[e]));
    }
}

__global__ void k_fsort(const int2* __restrict__ tmp, const int* __restrict__ gofs,
                        const int* __restrict__ blocksum,
                        int2* __restrict__ csr, int* __restrict__ row_ptr,
                        float* __restrict__ loop_ea, int N, int E, int NBK) {
    __shared__ int lcnt[256], lofs[256], lcur[256];
    __shared__ float lea[256];
    int bkt = blockIdx.x;
    int t = threadIdx.x;
    int base = gofs[bkt * 256] + blocksum[bkt];
    int endv = (bkt == NBK - 1) ? E : (gofs[(bkt + 1) * 256] + blocksum[bkt + 1]);
    int cnt = endv - base;
    if (t < 256) { lcnt[t] = 0; lea[t] = 0.0f; }
    __syncthreads();
    for (int i = t; i < cnt; i += 1024) {
        int2 e2 = tmp[base + i];
        unsigned dl = (unsigned)e2.x >> 24;
        atomicAdd(&lcnt[dl], 1);
        atomicAdd(&lea[dl], __int_as_float(e2.y));
    }
    __syncthreads();
    int v = (t < 256) ? lcnt[t] : 0;
    if (t < 256) lofs[t] = v;
    __syncthreads();
    #pragma unroll
    for (int off = 1; off < 256; off <<= 1) {
        int add = (t >= off && t < 256) ? lofs[t - off] : 0;
        __syncthreads();
        if (t < 256) lofs[t] += add;
        __syncthreads();
    }
    if (t < 256) {
        int excl = lofs[t] - v;
        int nlo = bkt << 8;
        if (nlo + t < N) {
            row_ptr[nlo + t] = base + excl;
            loop_ea[nlo + t] = lea[t] / fmaxf((float)v, 1.0f);
        }
        lcur[t] = base + excl;
    }
    __syncthreads();
    for (int i = t; i < cnt; i += 1024) {
        int2 e2 = tmp[base + i];
        int dl = (unsigned)e2.x >> 24;
        int pos = atomicAdd(&lcur[dl], 1);
        csr[pos] = make_int2(e2.x & 0x00FFFFFF, e2.y);
    }
    if (bkt == 0 && t == 0) row_ptr[N] = E;
}

// ---------------- layer 1 (fused with layer-2 linear) ----------------

// One wave per dst node, lane = 2 channels; node wave-uniform -> scalar s_loads.
// Fused tail: wave transposes its 128 h-values through its own LDS slice
// (no block barrier needed), lane (j=lane>>3, sub=lane&7) sums 16 k's from
// k-major Wint (8 j-lanes per cache line -> coalesced), 8-lane DPP butterfly.
__global__ void k_l1_node(const int2* __restrict__ csr, const int* __restrict__ row_ptr,
                          const float* __restrict__ x, const float* __restrict__ loop_ea,
                          const float* __restrict__ Wl1, const float* __restrict__ bl1,
                          const float* __restrict__ Wr1, const float* __restrict__ br1,
                          const float* __restrict__ We1, const float* __restrict__ att1,
                          const float* __restrict__ bias1, const f32x2* __restrict__ Wint,
                          const float* __restrict__ bl2, const float* __restrict__ br2,
                          float* __restrict__ xl2, float* __restrict__ xr2, int N) {
    __shared__ float hs[4][128];
    int wid = threadIdx.x >> 6;
    int lane = threadIdx.x & 63;
    int node = blockIdx.x * 4 + wid;
    if (node >= N) return;
    node = __builtin_amdgcn_readfirstlane(node);

    const f32x2* Wl1v = (const f32x2*)Wl1;
    f32x2 wl0 = Wl1v[lane],        wl1v = Wl1v[64 + lane];
    f32x2 wl2v = Wl1v[128 + lane], wl3v = Wl1v[192 + lane];
    f32x2 b2 = ((const f32x2*)bl1)[lane];
    float4 xv = *(const float4*)(x + (size_t)node * 4);
    const f32x2* Wr1v = (const f32x2*)Wr1;
    f32x2 rr = ((const f32x2*)br1)[lane];
    rr = pkfma(sp(xv.x), Wr1v[lane],       rr);
    rr = pkfma(sp(xv.y), Wr1v[64 + lane],  rr);
    rr = pkfma(sp(xv.z), Wr1v[128 + lane], rr);
    rr = pkfma(sp(xv.w), Wr1v[192 + lane], rr);
    f32x2 we2 = ((const f32x2*)We1)[lane];
    f32x2 at2 = ((const f32x2*)att1)[lane] * LOG2E;   // fold exp -> exp2
    const char* xb = (const char*)x;

    #define VL2(xs) pkfma(sp((xs).w), wl3v, pkfma(sp((xs).z), wl2v, \
                    pkfma(sp((xs).y), wl1v, pkfma(sp((xs).x), wl0, b2))))
    #define LOGIT(xs, ee, vl, aa) \
        f32x2 vl = VL2(xs); \
        float aa; \
        { f32x2 m_ = lrelu2(pkfma(sp(ee), we2, vl + rr)); \
          f32x2 q_ = m_ * at2; \
          float p_ = q_.x + q_.y; RED8(p_); aa = fexp2(p_); }

    int start = row_ptr[node];
    int deg   = row_ptr[node + 1] - start;
    const int2* crow = csr + start;

    // self-loop
    float eav = loop_ea[node];
    LOGIT(xv, eav, vls, a);
    float den = a;
    f32x2 acc = sp(a) * vls;
    int k = 0;
    for (; k + 8 <= deg; k += 8) {
        int2 q0 = crow[k],     q1 = crow[k + 1], q2 = crow[k + 2], q3 = crow[k + 3];
        int2 q4 = crow[k + 4], q5 = crow[k + 5], q6 = crow[k + 6], q7 = crow[k + 7];
        float4 y0 = *(const float4*)(xb + (unsigned)q0.x);
        float4 y1 = *(const float4*)(xb + (unsigned)q1.x);
        float4 y2 = *(const float4*)(xb + (unsigned)q2.x);
        float4 y3 = *(const float4*)(xb + (unsigned)q3.x);
        float4 y4 = *(const float4*)(xb + (unsigned)q4.x);
        float4 y5 = *(const float4*)(xb + (unsigned)q5.x);
        float4 y6 = *(const float4*)(xb + (unsigned)q6.x);
        float4 y7 = *(const float4*)(xb + (unsigned)q7.x);
        LOGIT(y0, __int_as_float(q0.y), ul0, b0);
        LOGIT(y1, __int_as_float(q1.y), ul1, b1);
        LOGIT(y2, __int_as_float(q2.y), ul2, bb2);
        LOGIT(y3, __int_as_float(q3.y), ul3, b3);
        LOGIT(y4, __int_as_float(q4.y), ul4, b4);
        LOGIT(y5, __int_as_float(q5.y), ul5, b5);
        LOGIT(y6, __int_as_float(q6.y), ul6, b6);
        LOGIT(y7, __int_as_float(q7.y), ul7, b7);
        den += ((b0 + b1) + (bb2 + b3)) + ((b4 + b5) + (b6 + b7));
        acc = pkfma(sp(b0), ul0, acc);
        acc = pkfma(sp(b1), ul1, acc);
        acc = pkfma(sp(bb2), ul2, acc);
        acc = pkfma(sp(b3), ul3, acc);
        acc = pkfma(sp(b4), ul4, acc);
        acc = pkfma(sp(b5), ul5, acc);
        acc = pkfma(sp(b6), ul6, acc);
        acc = pkfma(sp(b7), ul7, acc);
    }
    for (; k + 4 <= deg; k += 4) {
        int2 pr0 = crow[k],     pr1 = crow[k + 1];
        int2 pr2 = crow[k + 2], pr3 = crow[k + 3];
        float4 x0 = *(const float4*)(xb + (unsigned)pr0.x);
        float4 x1 = *(const float4*)(xb + (unsigned)pr1.x);
        float4 x2 = *(const float4*)(xb + (unsigned)pr2.x);
        float4 x3 = *(const float4*)(xb + (unsigned)pr3.x);
        LOGIT(x0, __int_as_float(pr0.y), vl0, a0);
        LOGIT(x1, __int_as_float(pr1.y), vl1, a1);
        LOGIT(x2, __int_as_float(pr2.y), vl2, a2);
        LOGIT(x3, __int_as_float(pr3.y), vl3, a3);
        den += (a0 + a1) + (a2 + a3);
        acc = pkfma(sp(a0), vl0, acc);
        acc = pkfma(sp(a1), vl1, acc);
        acc = pkfma(sp(a2), vl2, acc);
        acc = pkfma(sp(a3), vl3, acc);
    }
    for (; k < deg; ++k) {
        int2 pr = crow[k];
        float4 xs = *(const float4*)(xb + (unsigned)pr.x);
        LOGIT(xs, __int_as_float(pr.y), vls2, aa);
        den += aa;
        acc = pkfma(sp(aa), vls2, acc);
    }
    #undef VL2
    #undef LOGIT
    f32x2 bia = ((const f32x2*)bias1)[lane];
    f32x2 o = pkfma(acc, sp(1.0f / den), bia);
    float o0 = elu1(o.x);
    float o1 = elu1(o.y);
    // per-wave LDS slice; same-wave DS ops are in-order -> no block barrier
    *(float2*)&hs[wid][lane * 2] = make_float2(o0, o1);

    // fused layer-2 linear: j = lane>>3, sub = lane&7 sums k = sub*16..sub*16+15
    // k-major Wint: element (k, j) at Wint[k*8 + j]; 8 j-lanes per cache line
    int j = lane >> 3, sub = lane & 7;
    const float* hrow = &hs[wid][sub * 16];
    const f32x2* wrow = Wint + sub * 128 + j;   // stride 8 between k's
    f32x2 a2 = {0.0f, 0.0f};
    #pragma unroll
    for (int kk = 0; kk < 16; kk += 4) {
        float4 hv = *(const float4*)(hrow + kk);
        a2 = pkfma(sp(hv.x), wrow[(kk)     * 8], a2);
        a2 = pkfma(sp(hv.y), wrow[(kk + 1) * 8], a2);
        a2 = pkfma(sp(hv.z), wrow[(kk + 2) * 8], a2);
        a2 = pkfma(sp(hv.w), wrow[(kk + 3) * 8], a2);
    }
    RED8(a2.x);
    RED8(a2.y);
    if (sub == 0) {
        xl2[(size_t)node * 8 + j] = a2.x + bl2[j];
        xr2[(size_t)node * 8 + j] = a2.y + br2[j];
    }
}

// ---------------- layer 2 ----------------

// 8 lanes per dst node, lane = edge within group. Per-lane local accumulation;
// single deferred 9-value DPP reduce per node (sums are linear).
__global__ void k_l2_node(const int2* __restrict__ csr, const int* __restrict__ row_ptr,
                          const float* __restrict__ xl2, const float* __restrict__ xr2,
                          const float* __restrict__ loop_ea,
                          const float* __restrict__ We2, const float* __restrict__ att2,
                          const float* __restrict__ bias2, float* __restrict__ h2, int N) {
    int t = blockIdx.x * blockDim.x + threadIdx.x;
    int node = t >> 3;
    int lane = t & 7;
    if (node >= N) return;
    float4 ra = *(const float4*)(xr2 + (size_t)node * 8);
    float4 rb = *(const float4*)(xr2 + (size_t)node * 8 + 4);
    f32x2 rv0 = {ra.x, ra.y}, rv1 = {ra.z, ra.w}, rv2 = {rb.x, rb.y}, rv3 = {rb.z, rb.w};
    f32x2 we0 = ((const f32x2*)We2)[0], we1 = ((const f32x2*)We2)[1];
    f32x2 we2v = ((const f32x2*)We2)[2], we3 = ((const f32x2*)We2)[3];
    f32x2 at0 = ((const f32x2*)att2)[0] * LOG2E, at1 = ((const f32x2*)att2)[1] * LOG2E;
    f32x2 at2v = ((const f32x2*)att2)[2] * LOG2E, at3 = ((const f32x2*)att2)[3] * LOG2E;
    const char* xlb = (const char*)xl2;
    int start = row_ptr[node], deg = row_ptr[node + 1] - start;
    int total = deg + 1;          // + self loop
    float den = 0.0f;
    f32x2 ac0 = {0,0}, ac1 = {0,0}, ac2 = {0,0}, ac3 = {0,0};
    for (int base = 0; base < total; base += 8) {
        int e = base + lane;
        if (e < total) {
            const float* lp;
            float eav;
            if (e < deg) {
                int2 pr = csr[start + e];
                lp = (const float*)(xlb + 2u * (unsigned)pr.x);   // src*32 bytes
                eav = __int_as_float(pr.y);
            } else {
                lp = xl2 + (size_t)node * 8;
                eav = loop_ea[node];
            }
            float4 la = *(const float4*)lp;
            float4 lb = *(const float4*)(lp + 4);
            f32x2 l0 = {la.x, la.y}, l1 = {la.z, la.w};
            f32x2 l2 = {lb.x, lb.y}, l3 = {lb.z, lb.w};
            f32x2 ev = sp(eav);
            f32x2 q = lrelu2(pkfma(ev, we0, l0 + rv0)) * at0;
            q = pkfma(lrelu2(pkfma(ev, we1, l1 + rv1)), at1, q);
            q = pkfma(lrelu2(pkfma(ev, we2v, l2 + rv2)), at2v, q);
            q = pkfma(lrelu2(pkfma(ev, we3, l3 + rv3)), at3, q);
            float a = fexp2(q.x + q.y);
            den += a;
            f32x2 av = sp(a);
            ac0 = pkfma(av, l0, ac0);
            ac1 = pkfma(av, l1, ac1);
            ac2 = pkfma(av, l2, ac2);
            ac3 = pkfma(av, l3, ac3);
        }
    }
    // single deferred reduction across the 8-lane group
    RED8(den);
    float w0 = ac0.x, w1 = ac0.y, w2 = ac1.x, w3 = ac1.y;
    float w4 = ac2.x, w5 = ac2.y, w6 = ac3.x, w7 = ac3.y;
    RED8(w0); RED8(w1); RED8(w2); RED8(w3);
    RED8(w4); RED8(w5); RED8(w6); RED8(w7);
    if (lane == 0) {
        float inv = 1.0f / den;
        float o[8] = {w0, w1, w2, w3, w4, w5, w6, w7};
        #pragma unroll
        for (int cc = 0; cc < 8; ++cc) {
            float v = fmaf(o[cc], inv, bias2[cc]);
            o[cc] = elu1(v);
        }
        *(float4*)(h2 + (size_t)node * 8)     = make_float4(o[0], o[1], o[2], o[3]);
        *(float4*)(h2 + (size_t)node * 8 + 4) = make_float4(o[4], o[5], o[6], o[7]);
    }
}

// One block per graph; batch is sorted -> binary-search the segment.
__global__ void k_pool(const float* __restrict__ h2, const int* __restrict__ batch,
                       const float* __restrict__ W3, const float* __restrict__ b3,
                       float* __restrict__ out, int N) {
    int g = blockIdx.x;
    int lo = 0, hi = N;
    while (lo < hi) { int mid = (lo + hi) >> 1; if (batch[mid] < g) lo = mid + 1; else hi = mid; }
    int start = lo;
    int lo2 = start, hi2 = N;
    while (lo2 < hi2) { int mid = (lo2 + hi2) >> 1; if (batch[mid] < g + 1) lo2 = mid + 1; else hi2 = mid; }
    int end = lo2;
    int cnt = end - start;
    int t = threadIdx.x;
    int c = t & 7, rg = t >> 3;
    float s = 0.0f;
    for (int i = start + rg; i < end; i += 32) s += h2[(size_t)i * 8 + c];
    __shared__ float sm[256];
    sm[t] = s;
    __syncthreads();
    #pragma unroll
    for (int off = 16; off >= 1; off >>= 1) {
        if (rg < off) sm[t] += sm[t + off * 8];
        __syncthreads();
    }
    if (t == 0) {
        float inv = 1.0f / fmaxf((float)cnt, 1.0f);
        float acc = b3[0];
        #pragma unroll
        for (int cc = 0; cc < 8; ++cc) acc = fmaf(sm[cc] * inv, W3[cc], acc);
        out[g] = acc;
    }
}

extern "C" void kernel_launch(void* const* d_in, const int* in_sizes, int n_in,
                              void* d_out, int out_size, void* d_ws, size_t ws_size,
                              hipStream_t stream) {
    const float* x     = (const float*)d_in[0];
    const int*   ei    = (const int*)d_in[1];
    const float* ea    = (const float*)d_in[2];
    const int*   batch = (const int*)d_in[3];
    const float* Wl1 = (const float*)d_in[4];
    const float* bl1 = (const float*)d_in[5];
    const float* Wr1 = (const float*)d_in[6];
    const float* br1 = (const float*)d_in[7];
    const float* We1 = (const float*)d_in[8];
    const float* att1 = (const float*)d_in[9];
    const float* bias1 = (const float*)d_in[10];
    const float* Wl2 = (const float*)d_in[11];
    const float* bl2 = (const float*)d_in[12];
    const float* Wr2 = (const float*)d_in[13];
    const float* br2 = (const float*)d_in[14];
    const float* We2 = (const float*)d_in[15];
    const float* att2 = (const float*)d_in[16];
    const float* bias2 = (const float*)d_in[17];
    const float* W3 = (const float*)d_in[18];
    const float* b3 = (const float*)d_in[19];

    const int N  = in_sizes[0] / 4;
    const int E  = in_sizes[1] / 2;
    const int G  = out_size;
    const int* src = ei;
    const int* dst = ei + E;

    const int NBK = (N + 255) >> 8;                      // buckets of 256 nodes, <= 256
    const int NCH = 256;                                 // edge chunks
    const int CE  = (((E + NCH - 1) / NCH) + 3) & ~3;    // edges per chunk, x4-aligned
    const int L   = NBK * 256;                           // count-matrix length

    #define ALIGN4(v) (((v) + 3) & ~3)
    int* w = (int*)d_ws;
    int* gofs     = w; w += ALIGN4(L + 1);
    int* blocksum = w; w += 256;
    int* row_ptr  = w; w += ALIGN4(N + 1);
    float* loop_ea = (float*)w; w += ALIGN4(N);
    float* xl2 = (float*)w; w += (size_t)N * 8;
    float* xr2 = (float*)w; w += (size_t)N * 8;
    float* h2  = (float*)w; w += (size_t)N * 8;
    float2* Wint = (float2*)w; w += 2048;
    int2* tmp = (int2*)w; w += (size_t)E * 2;
    int2* csr = (int2*)w; w += (size_t)E * 2;
    #undef ALIGN4

    // CSR build: two-level counting sort (block-offset add folded into consumers)
    k_bcnt<<<NCH, 1024, 0, stream>>>(dst, gofs, E, CE, NBK);
    k_scan1<<<NBK, 256, 0, stream>>>(gofs, gofs, blocksum, L);
    k_scan2<<<1, 256, 0, stream>>>(blocksum, NBK, Wl2, Wr2, Wint);
    k_part<<<NCH, 1024, 0, stream>>>(src, dst, ea, gofs, blocksum, tmp, E, CE, NBK);
    k_fsort<<<NBK, 1024, 0, stream>>>(tmp, gofs, blocksum, csr, row_ptr, loop_ea, N, E, NBK);

    // layer 1 (+ fused layer-2 linear; h1 never touches HBM)
    k_l1_node<<<(N + 3) / 4, 256, 0, stream>>>(csr, row_ptr, x, loop_ea,
                                               Wl1, bl1, Wr1, br1, We1, att1, bias1,
                                               (const f32x2*)Wint, bl2, br2, xl2, xr2, N);
    // layer 2
    k_l2_node<<<((size_t)N * 8 + 255) / 256, 256, 0, stream>>>(csr, row_ptr, xl2, xr2,
                                                               loop_ea, We2, att2, bias2, h2, N);
    // pool + final linear
    k_pool<<<G, 256, 0, stream>>>(h2, batch, W3, b3, (float*)d_out, N);
}

// Round 20
// 131.242 us; speedup vs baseline: 1.2730x; 1.2730x over previous
//
#include <hip/hip_runtime.h>
#include <math.h>

#define LOG2E 1.44269504088896340736f

typedef float f32x2 __attribute__((ext_vector_type(2)));
__device__ __forceinline__ f32x2 pkfma(f32x2 a, f32x2 b, f32x2 c) {
    return __builtin_elementwise_fma(a, b, c);
}
__device__ __forceinline__ f32x2 sp(float s) { f32x2 v = {s, s}; return v; }
__device__ __forceinline__ f32x2 lrelu2(f32x2 m) {
    return __builtin_elementwise_max(m, 0.2f * m);
}
// raw v_exp_f32 (single inst); logits/activations are O(1) so denorm path irrelevant
__device__ __forceinline__ float fexp2(float x) {
    float r;
    asm("v_exp_f32 %0, %1" : "=v"(r) : "v"(x));
    return r;
}
// elu via raw exp2: v>0 ? v : e^v-1
__device__ __forceinline__ float elu1(float v) {
    return v > 0.0f ? v : fexp2(v * LOG2E) - 1.0f;
}

// butterfly add via DPP (pure VALU, no LDS): xor1=quad_perm[1,0,3,2],
// xor2=quad_perm[2,3,0,1], 8-lane mirror = row_half_mirror
#define DPPADD(p, ctrl) \
    p += __int_as_float(__builtin_amdgcn_mov_dpp(__float_as_int(p), ctrl, 0xF, 0xF, true))
#define RED8(p) do { DPPADD(p, 0xB1); DPPADD(p, 0x4E); DPPADD(p, 0x141); } while (0)

// ---------------- CSR build: two-level counting sort (no global atomics) ----

__global__ void k_bcnt(const int* __restrict__ dst, int* __restrict__ cntmat,
                       int E, int CE, int NBK) {
    __shared__ int cnt[256];
    int t = threadIdx.x;
    if (t < 256) cnt[t] = 0;
    __syncthreads();
    int c = blockIdx.x;
    int lo = c * CE, hi = min(E, lo + CE);
    int len = hi - lo; if (len < 0) len = 0;
    int len4 = len & ~3;
    for (int o = t * 4; o < len4; o += 4096) {
        int4 d4 = *(const int4*)(dst + lo + o);
        atomicAdd(&cnt[d4.x >> 8], 1);
        atomicAdd(&cnt[d4.y >> 8], 1);
        atomicAdd(&cnt[d4.z >> 8], 1);
        atomicAdd(&cnt[d4.w >> 8], 1);
    }
    for (int o = len4 + t; o < len; o += 1024)
        atomicAdd(&cnt[dst[lo + o] >> 8], 1);
    __syncthreads();
    if (t < NBK) cntmat[t * 256 + c] = cnt[t];
}

__global__ void k_scan1(const int* __restrict__ in, int* __restrict__ out,
                        int* __restrict__ blocksum, int L) {
    __shared__ int sm[256];
    int t = threadIdx.x;
    int i = blockIdx.x * 256 + t;
    int v = (i < L) ? in[i] : 0;
    sm[t] = v;
    __syncthreads();
    #pragma unroll
    for (int off = 1; off < 256; off <<= 1) {
        int add = (t >= off) ? sm[t - off] : 0;
        __syncthreads();
        sm[t] += add;
        __syncthreads();
    }
    if (i < L) out[i] = sm[t] - v;   // exclusive (block-local)
    if (t == 255) blocksum[blockIdx.x] = sm[255];
}

// scan block totals in place; idle threads also build the j-major W2 table:
// Wjk[j*128+k] = (Wl2[k][j], Wr2[k][j])
__global__ void k_scan2(int* __restrict__ blocksum, int nb,
                        const float* __restrict__ Wl2, const float* __restrict__ Wr2,
                        float2* __restrict__ Wjk) {
    __shared__ int sm[256];
    int t = threadIdx.x;
    int v = (t < nb) ? blocksum[t] : 0;
    sm[t] = v;
    __syncthreads();
    #pragma unroll
    for (int off = 1; off < 256; off <<= 1) {
        int add = (t >= off) ? sm[t - off] : 0;
        __syncthreads();
        sm[t] += add;
        __syncthreads();
    }
    if (t < nb) blocksum[t] = sm[t] - v;
    #pragma unroll
    for (int i = 0; i < 4; ++i) {
        int idx = t + i * 256;
        int j = idx >> 7, k = idx & 127;
        Wjk[idx] = make_float2(Wl2[k * 8 + j], Wr2[k * 8 + j]);
    }
}

__global__ void k_part(const int* __restrict__ src, const int* __restrict__ dst,
                       const float* __restrict__ ea, const int* __restrict__ gofs,
                       const int* __restrict__ blocksum,
                       int2* __restrict__ tmp, int E, int CE, int NBK) {
    __shared__ int cur[256];
    int t = threadIdx.x;
    int c = blockIdx.x;
    if (t < NBK) cur[t] = gofs[t * 256 + c] + blocksum[t];
    __syncthreads();
    int lo = c * CE, hi = min(E, lo + CE);
    int len = hi - lo; if (len < 0) len = 0;
    int len4 = len & ~3;
    for (int o = t * 4; o < len4; o += 4096) {
        int e = lo + o;
        int4 s4 = *(const int4*)(src + e);
        int4 d4 = *(const int4*)(dst + e);
        float4 a4 = *(const float4*)(ea + e);
        int p0 = atomicAdd(&cur[d4.x >> 8], 1);
        int p1 = atomicAdd(&cur[d4.y >> 8], 1);
        int p2 = atomicAdd(&cur[d4.z >> 8], 1);
        int p3 = atomicAdd(&cur[d4.w >> 8], 1);
        tmp[p0] = make_int2(((d4.x & 255) << 24) | (s4.x << 4), __float_as_int(a4.x));
        tmp[p1] = make_int2(((d4.y & 255) << 24) | (s4.y << 4), __float_as_int(a4.y));
        tmp[p2] = make_int2(((d4.z & 255) << 24) | (s4.z << 4), __float_as_int(a4.z));
        tmp[p3] = make_int2(((d4.w & 255) << 24) | (s4.w << 4), __float_as_int(a4.w));
    }
    for (int o = len4 + t; o < len; o += 1024) {
        int e = lo + o;
        int d = dst[e];
        int pos = atomicAdd(&cur[d >> 8], 1);
        tmp[pos] = make_int2(((d & 255) << 24) | (src[e] << 4), __float_as_int(ea[e]));
    }
}

__global__ void k_fsort(const int2* __restrict__ tmp, const int* __restrict__ gofs,
                        const int* __restrict__ blocksum,
                        int2* __restrict__ csr, int* __restrict__ row_ptr,
                        float* __restrict__ loop_ea, int N, int E, int NBK) {
    __shared__ int lcnt[256], lofs[256], lcur[256];
    __shared__ float lea[256];
    int bkt = blockIdx.x;
    int t = threadIdx.x;
    int base = gofs[bkt * 256] + blocksum[bkt];
    int endv = (bkt == NBK - 1) ? E : (gofs[(bkt + 1) * 256] + blocksum[bkt + 1]);
    int cnt = endv - base;
    if (t < 256) { lcnt[t] = 0; lea[t] = 0.0f; }
    __syncthreads();
    for (int i = t; i < cnt; i += 1024) {
        int2 e2 = tmp[base + i];
        unsigned dl = (unsigned)e2.x >> 24;
        atomicAdd(&lcnt[dl], 1);
        atomicAdd(&lea[dl], __int_as_float(e2.y));
    }
    __syncthreads();
    int v = (t < 256) ? lcnt[t] : 0;
    if (t < 256) lofs[t] = v;
    __syncthreads();
    #pragma unroll
    for (int off = 1; off < 256; off <<= 1) {
        int add = (t >= off && t < 256) ? lofs[t - off] : 0;
        __syncthreads();
        if (t < 256) lofs[t] += add;
        __syncthreads();
    }
    if (t < 256) {
        int excl = lofs[t] - v;
        int nlo = bkt << 8;
        if (nlo + t < N) {
            row_ptr[nlo + t] = base + excl;
            loop_ea[nlo + t] = lea[t] / fmaxf((float)v, 1.0f);
        }
        lcur[t] = base + excl;
    }
    __syncthreads();
    for (int i = t; i < cnt; i += 1024) {
        int2 e2 = tmp[base + i];
        int dl = (unsigned)e2.x >> 24;
        int pos = atomicAdd(&lcur[dl], 1);
        csr[pos] = make_int2(e2.x & 0x00FFFFFF, e2.y);
    }
    if (bkt == 0 && t == 0) row_ptr[N] = E;
}

// ---------------- layer 1 (fused with layer-2 linear) ----------------

// One wave per dst node, lane = 2 channels; node wave-uniform -> scalar s_loads.
// Fused tail: each lane's 16 Wjk weights are HOISTED INTO REGISTERS at entry
// (zero global loads in the tail); wave transposes its 128 h-values through
// its own LDS slice (no block barrier), 16 pkfma + 8-lane DPP butterfly.
__global__ void k_l1_node(const int2* __restrict__ csr, const int* __restrict__ row_ptr,
                          const float* __restrict__ x, const float* __restrict__ loop_ea,
                          const float* __restrict__ Wl1, const float* __restrict__ bl1,
                          const float* __restrict__ Wr1, const float* __restrict__ br1,
                          const float* __restrict__ We1, const float* __restrict__ att1,
                          const float* __restrict__ bias1, const f32x2* __restrict__ Wjk,
                          const float* __restrict__ bl2, const float* __restrict__ br2,
                          float* __restrict__ xl2, float* __restrict__ xr2, int N) {
    __shared__ float hs[4][128];
    int wid = threadIdx.x >> 6;
    int lane = threadIdx.x & 63;
    int node = blockIdx.x * 4 + wid;
    if (node >= N) return;
    node = __builtin_amdgcn_readfirstlane(node);

    // hoist this lane's Wjk slice into registers (16 f32x2, contiguous 128 B)
    int j = lane >> 3, sub = lane & 7;
    f32x2 wreg[16];
    {
        const f32x2* wsrc = Wjk + j * 128 + sub * 16;
        #pragma unroll
        for (int kk = 0; kk < 16; ++kk) wreg[kk] = wsrc[kk];
    }

    const f32x2* Wl1v = (const f32x2*)Wl1;
    f32x2 wl0 = Wl1v[lane],        wl1v = Wl1v[64 + lane];
    f32x2 wl2v = Wl1v[128 + lane], wl3v = Wl1v[192 + lane];
    f32x2 b2 = ((const f32x2*)bl1)[lane];
    float4 xv = *(const float4*)(x + (size_t)node * 4);
    const f32x2* Wr1v = (const f32x2*)Wr1;
    f32x2 rr = ((const f32x2*)br1)[lane];
    rr = pkfma(sp(xv.x), Wr1v[lane],       rr);
    rr = pkfma(sp(xv.y), Wr1v[64 + lane],  rr);
    rr = pkfma(sp(xv.z), Wr1v[128 + lane], rr);
    rr = pkfma(sp(xv.w), Wr1v[192 + lane], rr);
    f32x2 we2 = ((const f32x2*)We1)[lane];
    f32x2 at2 = ((const f32x2*)att1)[lane] * LOG2E;   // fold exp -> exp2
    const char* xb = (const char*)x;

    #define VL2(xs) pkfma(sp((xs).w), wl3v, pkfma(sp((xs).z), wl2v, \
                    pkfma(sp((xs).y), wl1v, pkfma(sp((xs).x), wl0, b2))))
    #define LOGIT(xs, ee, vl, aa) \
        f32x2 vl = VL2(xs); \
        float aa; \
        { f32x2 m_ = lrelu2(pkfma(sp(ee), we2, vl + rr)); \
          f32x2 q_ = m_ * at2; \
          float p_ = q_.x + q_.y; RED8(p_); aa = fexp2(p_); }

    int start = row_ptr[node];
    int deg   = row_ptr[node + 1] - start;
    const int2* crow = csr + start;

    // self-loop
    float eav = loop_ea[node];
    LOGIT(xv, eav, vls, a);
    float den = a;
    f32x2 acc = sp(a) * vls;
    int k = 0;
    for (; k + 8 <= deg; k += 8) {
        int2 q0 = crow[k],     q1 = crow[k + 1], q2 = crow[k + 2], q3 = crow[k + 3];
        int2 q4 = crow[k + 4], q5 = crow[k + 5], q6 = crow[k + 6], q7 = crow[k + 7];
        float4 y0 = *(const float4*)(xb + (unsigned)q0.x);
        float4 y1 = *(const float4*)(xb + (unsigned)q1.x);
        float4 y2 = *(const float4*)(xb + (unsigned)q2.x);
        float4 y3 = *(const float4*)(xb + (unsigned)q3.x);
        float4 y4 = *(const float4*)(xb + (unsigned)q4.x);
        float4 y5 = *(const float4*)(xb + (unsigned)q5.x);
        float4 y6 = *(const float4*)(xb + (unsigned)q6.x);
        float4 y7 = *(const float4*)(xb + (unsigned)q7.x);
        LOGIT(y0, __int_as_float(q0.y), ul0, b0);
        LOGIT(y1, __int_as_float(q1.y), ul1, b1);
        LOGIT(y2, __int_as_float(q2.y), ul2, bb2);
        LOGIT(y3, __int_as_float(q3.y), ul3, b3);
        LOGIT(y4, __int_as_float(q4.y), ul4, b4);
        LOGIT(y5, __int_as_float(q5.y), ul5, b5);
        LOGIT(y6, __int_as_float(q6.y), ul6, b6);
        LOGIT(y7, __int_as_float(q7.y), ul7, b7);
        den += ((b0 + b1) + (bb2 + b3)) + ((b4 + b5) + (b6 + b7));
        acc = pkfma(sp(b0), ul0, acc);
        acc = pkfma(sp(b1), ul1, acc);
        acc = pkfma(sp(bb2), ul2, acc);
        acc = pkfma(sp(b3), ul3, acc);
        acc = pkfma(sp(b4), ul4, acc);
        acc = pkfma(sp(b5), ul5, acc);
        acc = pkfma(sp(b6), ul6, acc);
        acc = pkfma(sp(b7), ul7, acc);
    }
    for (; k + 4 <= deg; k += 4) {
        int2 pr0 = crow[k],     pr1 = crow[k + 1];
        int2 pr2 = crow[k + 2], pr3 = crow[k + 3];
        float4 x0 = *(const float4*)(xb + (unsigned)pr0.x);
        float4 x1 = *(const float4*)(xb + (unsigned)pr1.x);
        float4 x2 = *(const float4*)(xb + (unsigned)pr2.x);
        float4 x3 = *(const float4*)(xb + (unsigned)pr3.x);
        LOGIT(x0, __int_as_float(pr0.y), vl0, a0);
        LOGIT(x1, __int_as_float(pr1.y), vl1, a1);
        LOGIT(x2, __int_as_float(pr2.y), vl2, a2);
        LOGIT(x3, __int_as_float(pr3.y), vl3, a3);
        den += (a0 + a1) + (a2 + a3);
        acc = pkfma(sp(a0), vl0, acc);
        acc = pkfma(sp(a1), vl1, acc);
        acc = pkfma(sp(a2), vl2, acc);
        acc = pkfma(sp(a3), vl3, acc);
    }
    for (; k < deg; ++k) {
        int2 pr = crow[k];
        float4 xs = *(const float4*)(xb + (unsigned)pr.x);
        LOGIT(xs, __int_as_float(pr.y), vls2, aa);
        den += aa;
        acc = pkfma(sp(aa), vls2, acc);
    }
    #undef VL2
    #undef LOGIT
    f32x2 bia = ((const f32x2*)bias1)[lane];
    f32x2 o = pkfma(acc, sp(1.0f / den), bia);
    float o0 = elu1(o.x);
    float o1 = elu1(o.y);
    // per-wave LDS slice; same-wave DS ops are in-order -> no block barrier
    *(float2*)&hs[wid][lane * 2] = make_float2(o0, o1);

    // fused layer-2 linear: zero global loads (weights in wreg)
    const float* hrow = &hs[wid][sub * 16];
    f32x2 a2 = {0.0f, 0.0f};
    #pragma unroll
    for (int kk = 0; kk < 16; kk += 4) {
        float4 hv = *(const float4*)(hrow + kk);
        a2 = pkfma(sp(hv.x), wreg[kk],     a2);
        a2 = pkfma(sp(hv.y), wreg[kk + 1], a2);
        a2 = pkfma(sp(hv.z), wreg[kk + 2], a2);
        a2 = pkfma(sp(hv.w), wreg[kk + 3], a2);
    }
    RED8(a2.x);
    RED8(a2.y);
    if (sub == 0) {
        xl2[(size_t)node * 8 + j] = a2.x + bl2[j];
        xr2[(size_t)node * 8 + j] = a2.y + br2[j];
    }
}

// ---------------- layer 2 ----------------

// 8 lanes per dst node, lane = edge within group. Per-lane local accumulation;
// single deferred 9-value DPP reduce per node (sums are linear).
__global__ void k_l2_node(const int2* __restrict__ csr, const int* __restrict__ row_ptr,
                          const float* __restrict__ xl2, const float* __restrict__ xr2,
                          const float* __restrict__ loop_ea,
                          const float* __restrict__ We2, const float* __restrict__ att2,
                          const float* __restrict__ bias2, float* __restrict__ h2, int N) {
    int t = blockIdx.x * blockDim.x + threadIdx.x;
    int node = t >> 3;
    int lane = t & 7;
    if (node >= N) return;
    float4 ra = *(const float4*)(xr2 + (size_t)node * 8);
    float4 rb = *(const float4*)(xr2 + (size_t)node * 8 + 4);
    f32x2 rv0 = {ra.x, ra.y}, rv1 = {ra.z, ra.w}, rv2 = {rb.x, rb.y}, rv3 = {rb.z, rb.w};
    f32x2 we0 = ((const f32x2*)We2)[0], we1 = ((const f32x2*)We2)[1];
    f32x2 we2v = ((const f32x2*)We2)[2], we3 = ((const f32x2*)We2)[3];
    f32x2 at0 = ((const f32x2*)att2)[0] * LOG2E, at1 = ((const f32x2*)att2)[1] * LOG2E;
    f32x2 at2v = ((const f32x2*)att2)[2] * LOG2E, at3 = ((const f32x2*)att2)[3] * LOG2E;
    const char* xlb = (const char*)xl2;
    int start = row_ptr[node], deg = row_ptr[node + 1] - start;
    int total = deg + 1;          // + self loop
    float den = 0.0f;
    f32x2 ac0 = {0,0}, ac1 = {0,0}, ac2 = {0,0}, ac3 = {0,0};
    for (int base = 0; base < total; base += 8) {
        int e = base + lane;
        if (e < total) {
            const float* lp;
            float eav;
            if (e < deg) {
                int2 pr = csr[start + e];
                lp = (const float*)(xlb + 2u * (unsigned)pr.x);   // src*32 bytes
                eav = __int_as_float(pr.y);
            } else {
                lp = xl2 + (size_t)node * 8;
                eav = loop_ea[node];
            }
            float4 la = *(const float4*)lp;
            float4 lb = *(const float4*)(lp + 4);
            f32x2 l0 = {la.x, la.y}, l1 = {la.z, la.w};
            f32x2 l2 = {lb.x, lb.y}, l3 = {lb.z, lb.w};
            f32x2 ev = sp(eav);
            f32x2 q = lrelu2(pkfma(ev, we0, l0 + rv0)) * at0;
            q = pkfma(lrelu2(pkfma(ev, we1, l1 + rv1)), at1, q);
            q = pkfma(lrelu2(pkfma(ev, we2v, l2 + rv2)), at2v, q);
            q = pkfma(lrelu2(pkfma(ev, we3, l3 + rv3)), at3, q);
            float a = fexp2(q.x + q.y);
            den += a;
            f32x2 av = sp(a);
            ac0 = pkfma(av, l0, ac0);
            ac1 = pkfma(av, l1, ac1);
            ac2 = pkfma(av, l2, ac2);
            ac3 = pkfma(av, l3, ac3);
        }
    }
    // single deferred reduction across the 8-lane group
    RED8(den);
    float w0 = ac0.x, w1 = ac0.y, w2 = ac1.x, w3 = ac1.y;
    float w4 = ac2.x, w5 = ac2.y, w6 = ac3.x, w7 = ac3.y;
    RED8(w0); RED8(w1); RED8(w2); RED8(w3);
    RED8(w4); RED8(w5); RED8(w6); RED8(w7);
    if (lane == 0) {
        float inv = 1.0f / den;
        float o[8] = {w0, w1, w2, w3, w4, w5, w6, w7};
        #pragma unroll
        for (int cc = 0; cc < 8; ++cc) {
            float v = fmaf(o[cc], inv, bias2[cc]);
            o[cc] = elu1(v);
        }
        *(float4*)(h2 + (size_t)node * 8)     = make_float4(o[0], o[1], o[2], o[3]);
        *(float4*)(h2 + (size_t)node * 8 + 4) = make_float4(o[4], o[5], o[6], o[7]);
    }
}

// One block per graph; batch is sorted -> binary-search the segment.
__global__ void k_pool(const float* __restrict__ h2, const int* __restrict__ batch,
                       const float* __restrict__ W3, const float* __restrict__ b3,
                       float* __restrict__ out, int N) {
    int g = blockIdx.x;
    int lo = 0, hi = N;
    while (lo < hi) { int mid = (lo + hi) >> 1; if (batch[mid] < g) lo = mid + 1; else hi = mid; }
    int start = lo;
    int lo2 = start, hi2 = N;
    while (lo2 < hi2) { int mid = (lo2 + hi2) >> 1; if (batch[mid] < g + 1) lo2 = mid + 1; else hi2 = mid; }
    int end = lo2;
    int cnt = end - start;
    int t = threadIdx.x;
    int c = t & 7, rg = t >> 3;
    float s = 0.0f;
    for (int i = start + rg; i < end; i += 32) s += h2[(size_t)i * 8 + c];
    __shared__ float sm[256];
    sm[t] = s;
    __syncthreads();
    #pragma unroll
    for (int off = 16; off >= 1; off >>= 1) {
        if (rg < off) sm[t] += sm[t + off * 8];
        __syncthreads();
    }
    if (t == 0) {
        float inv = 1.0f / fmaxf((float)cnt, 1.0f);
        float acc = b3[0];
        #pragma unroll
        for (int cc = 0; cc < 8; ++cc) acc = fmaf(sm[cc] * inv, W3[cc], acc);
        out[g] = acc;
    }
}

extern "C" void kernel_launch(void* const* d_in, const int* in_sizes, int n_in,
                              void* d_out, int out_size, void* d_ws, size_t ws_size,
                              hipStream_t stream) {
    const float* x     = (const float*)d_in[0];
    const int*   ei    = (const int*)d_in[1];
    const float* ea    = (const float*)d_in[2];
    const int*   batch = (const int*)d_in[3];
    const float* Wl1 = (const float*)d_in[4];
    const float* bl1 = (const float*)d_in[5];
    const float* Wr1 = (const float*)d_in[6];
    const float* br1 = (const float*)d_in[7];
    const float* We1 = (const float*)d_in[8];
    const float* att1 = (const float*)d_in[9];
    const float* bias1 = (const float*)d_in[10];
    const float* Wl2 = (const float*)d_in[11];
    const float* bl2 = (const float*)d_in[12];
    const float* Wr2 = (const float*)d_in[13];
    const float* br2 = (const float*)d_in[14];
    const float* We2 = (const float*)d_in[15];
    const float* att2 = (const float*)d_in[16];
    const float* bias2 = (const float*)d_in[17];
    const float* W3 = (const float*)d_in[18];
    const float* b3 = (const float*)d_in[19];

    const int N  = in_sizes[0] / 4;
    const int E  = in_sizes[1] / 2;
    const int G  = out_size;
    const int* src = ei;
    const int* dst = ei + E;

    const int NBK = (N + 255) >> 8;                      // buckets of 256 nodes, <= 256
    const int NCH = 256;                                 // edge chunks
    const int CE  = (((E + NCH - 1) / NCH) + 3) & ~3;    // edges per chunk, x4-aligned
    const int L   = NBK * 256;                           // count-matrix length

    #define ALIGN4(v) (((v) + 3) & ~3)
    int* w = (int*)d_ws;
    int* gofs     = w; w += ALIGN4(L + 1);
    int* blocksum = w; w += 256;
    int* row_ptr  = w; w += ALIGN4(N + 1);
    float* loop_ea = (float*)w; w += ALIGN4(N);
    float* xl2 = (float*)w; w += (size_t)N * 8;
    float* xr2 = (float*)w; w += (size_t)N * 8;
    float* h2  = (float*)w; w += (size_t)N * 8;
    float2* Wjk = (float2*)w; w += 2048;
    int2* tmp = (int2*)w; w += (size_t)E * 2;
    int2* csr = (int2*)w; w += (size_t)E * 2;
    #undef ALIGN4

    // CSR build: two-level counting sort (block-offset add folded into consumers)
    k_bcnt<<<NCH, 1024, 0, stream>>>(dst, gofs, E, CE, NBK);
    k_scan1<<<NBK, 256, 0, stream>>>(gofs, gofs, blocksum, L);
    k_scan2<<<1, 256, 0, stream>>>(blocksum, NBK, Wl2, Wr2, Wjk);
    k_part<<<NCH, 1024, 0, stream>>>(src, dst, ea, gofs, blocksum, tmp, E, CE, NBK);
    k_fsort<<<NBK, 1024, 0, stream>>>(tmp, gofs, blocksum, csr, row_ptr, loop_ea, N, E, NBK);

    // layer 1 (+ fused layer-2 linear; h1 never touches HBM)
    k_l1_node<<<(N + 3) / 4, 256, 0, stream>>>(csr, row_ptr, x, loop_ea,
                                               Wl1, bl1, Wr1, br1, We1, att1, bias1,
                                               (const f32x2*)Wjk, bl2, br2, xl2, xr2, N);
    // layer 2
    k_l2_node<<<((size_t)N * 8 + 255) / 256, 256, 0, stream>>>(csr, row_ptr, xl2, xr2,
                                                               loop_ea, We2, att2, bias2, h2, N);
    // pool + final linear
    k_pool<<<G, 256, 0, stream>>>(h2, batch, W3, b3, (float*)d_out, N);
}

// Round 21
// 100.387 us; speedup vs baseline: 1.6643x; 1.3074x over previous
//
#include <hip/hip_runtime.h>
#include <math.h>

#define LOG2E 1.44269504088896340736f

typedef float f32x2 __attribute__((ext_vector_type(2)));
__device__ __forceinline__ f32x2 pkfma(f32x2 a, f32x2 b, f32x2 c) {
    return __builtin_elementwise_fma(a, b, c);
}
__device__ __forceinline__ f32x2 sp(float s) { f32x2 v = {s, s}; return v; }
__device__ __forceinline__ f32x2 lrelu2(f32x2 m) {
    return __builtin_elementwise_max(m, 0.2f * m);
}
// raw v_exp_f32 (single inst); logits/activations are O(1) so denorm path irrelevant
__device__ __forceinline__ float fexp2(float x) {
    float r;
    asm("v_exp_f32 %0, %1" : "=v"(r) : "v"(x));
    return r;
}
// elu via raw exp2: v>0 ? v : e^v-1
__device__ __forceinline__ float elu1(float v) {
    return v > 0.0f ? v : fexp2(v * LOG2E) - 1.0f;
}

// butterfly add via DPP (pure VALU, no LDS): xor1=quad_perm[1,0,3,2],
// xor2=quad_perm[2,3,0,1], 8-lane mirror = row_half_mirror
#define DPPADD(p, ctrl) \
    p += __int_as_float(__builtin_amdgcn_mov_dpp(__float_as_int(p), ctrl, 0xF, 0xF, true))
#define RED8(p) do { DPPADD(p, 0xB1); DPPADD(p, 0x4E); DPPADD(p, 0x141); } while (0)

// ---------------- CSR build: two-level counting sort (no global atomics) ----

__global__ void k_bcnt(const int* __restrict__ dst, int* __restrict__ cntmat,
                       int E, int CE, int NBK) {
    __shared__ int cnt[256];
    int t = threadIdx.x;
    if (t < 256) cnt[t] = 0;
    __syncthreads();
    int c = blockIdx.x;
    int lo = c * CE, hi = min(E, lo + CE);
    int len = hi - lo; if (len < 0) len = 0;
    int len4 = len & ~3;
    for (int o = t * 4; o < len4; o += 4096) {
        int4 d4 = *(const int4*)(dst + lo + o);
        atomicAdd(&cnt[d4.x >> 8], 1);
        atomicAdd(&cnt[d4.y >> 8], 1);
        atomicAdd(&cnt[d4.z >> 8], 1);
        atomicAdd(&cnt[d4.w >> 8], 1);
    }
    for (int o = len4 + t; o < len; o += 1024)
        atomicAdd(&cnt[dst[lo + o] >> 8], 1);
    __syncthreads();
    if (t < NBK) cntmat[t * 256 + c] = cnt[t];
}

__global__ void k_scan1(const int* __restrict__ in, int* __restrict__ out,
                        int* __restrict__ blocksum, int L) {
    __shared__ int sm[256];
    int t = threadIdx.x;
    int i = blockIdx.x * 256 + t;
    int v = (i < L) ? in[i] : 0;
    sm[t] = v;
    __syncthreads();
    #pragma unroll
    for (int off = 1; off < 256; off <<= 1) {
        int add = (t >= off) ? sm[t - off] : 0;
        __syncthreads();
        sm[t] += add;
        __syncthreads();
    }
    if (i < L) out[i] = sm[t] - v;   // exclusive (block-local)
    if (t == 255) blocksum[blockIdx.x] = sm[255];
}

// scan block totals in place; idle threads build the tail weight table in the
// LDS-friendly layout: Wtile[kk*64 + l] = (Wl2[k][j], Wr2[k][j]) with
// j = l>>3, k = (l&7) + kk*8  (kk in [0,16), l in [0,64))
__global__ void k_scan2(int* __restrict__ blocksum, int nb,
                        const float* __restrict__ Wl2, const float* __restrict__ Wr2,
                        float2* __restrict__ Wtile) {
    __shared__ int sm[256];
    int t = threadIdx.x;
    int v = (t < nb) ? blocksum[t] : 0;
    sm[t] = v;
    __syncthreads();
    #pragma unroll
    for (int off = 1; off < 256; off <<= 1) {
        int add = (t >= off) ? sm[t - off] : 0;
        __syncthreads();
        sm[t] += add;
        __syncthreads();
    }
    if (t < nb) blocksum[t] = sm[t] - v;
    #pragma unroll
    for (int i = 0; i < 4; ++i) {
        int idx = t + i * 256;
        int kk = idx >> 6, l = idx & 63;
        int j = l >> 3, sub = l & 7;
        int k = sub + kk * 8;
        Wtile[idx] = make_float2(Wl2[k * 8 + j], Wr2[k * 8 + j]);
    }
}

__global__ void k_part(const int* __restrict__ src, const int* __restrict__ dst,
                       const float* __restrict__ ea, const int* __restrict__ gofs,
                       const int* __restrict__ blocksum,
                       int2* __restrict__ tmp, int E, int CE, int NBK) {
    __shared__ int cur[256];
    int t = threadIdx.x;
    int c = blockIdx.x;
    if (t < NBK) cur[t] = gofs[t * 256 + c] + blocksum[t];
    __syncthreads();
    int lo = c * CE, hi = min(E, lo + CE);
    int len = hi - lo; if (len < 0) len = 0;
    int len4 = len & ~3;
    for (int o = t * 4; o < len4; o += 4096) {
        int e = lo + o;
        int4 s4 = *(const int4*)(src + e);
        int4 d4 = *(const int4*)(dst + e);
        float4 a4 = *(const float4*)(ea + e);
        int p0 = atomicAdd(&cur[d4.x >> 8], 1);
        int p1 = atomicAdd(&cur[d4.y >> 8], 1);
        int p2 = atomicAdd(&cur[d4.z >> 8], 1);
        int p3 = atomicAdd(&cur[d4.w >> 8], 1);
        tmp[p0] = make_int2(((d4.x & 255) << 24) | (s4.x << 4), __float_as_int(a4.x));
        tmp[p1] = make_int2(((d4.y & 255) << 24) | (s4.y << 4), __float_as_int(a4.y));
        tmp[p2] = make_int2(((d4.z & 255) << 24) | (s4.z << 4), __float_as_int(a4.z));
        tmp[p3] = make_int2(((d4.w & 255) << 24) | (s4.w << 4), __float_as_int(a4.w));
    }
    for (int o = len4 + t; o < len; o += 1024) {
        int e = lo + o;
        int d = dst[e];
        int pos = atomicAdd(&cur[d >> 8], 1);
        tmp[pos] = make_int2(((d & 255) << 24) | (src[e] << 4), __float_as_int(ea[e]));
    }
}

__global__ void k_fsort(const int2* __restrict__ tmp, const int* __restrict__ gofs,
                        const int* __restrict__ blocksum,
                        int2* __restrict__ csr, int* __restrict__ row_ptr,
                        float* __restrict__ loop_ea, int N, int E, int NBK) {
    __shared__ int lcnt[256], lofs[256], lcur[256];
    __shared__ float lea[256];
    int bkt = blockIdx.x;
    int t = threadIdx.x;
    int base = gofs[bkt * 256] + blocksum[bkt];
    int endv = (bkt == NBK - 1) ? E : (gofs[(bkt + 1) * 256] + blocksum[bkt + 1]);
    int cnt = endv - base;
    if (t < 256) { lcnt[t] = 0; lea[t] = 0.0f; }
    __syncthreads();
    for (int i = t; i < cnt; i += 1024) {
        int2 e2 = tmp[base + i];
        unsigned dl = (unsigned)e2.x >> 24;
        atomicAdd(&lcnt[dl], 1);
        atomicAdd(&lea[dl], __int_as_float(e2.y));
    }
    __syncthreads();
    int v = (t < 256) ? lcnt[t] : 0;
    if (t < 256) lofs[t] = v;
    __syncthreads();
    #pragma unroll
    for (int off = 1; off < 256; off <<= 1) {
        int add = (t >= off && t < 256) ? lofs[t - off] : 0;
        __syncthreads();
        if (t < 256) lofs[t] += add;
        __syncthreads();
    }
    if (t < 256) {
        int excl = lofs[t] - v;
        int nlo = bkt << 8;
        if (nlo + t < N) {
            row_ptr[nlo + t] = base + excl;
            loop_ea[nlo + t] = lea[t] / fmaxf((float)v, 1.0f);
        }
        lcur[t] = base + excl;
    }
    __syncthreads();
    for (int i = t; i < cnt; i += 1024) {
        int2 e2 = tmp[base + i];
        int dl = (unsigned)e2.x >> 24;
        int pos = atomicAdd(&lcur[dl], 1);
        csr[pos] = make_int2(e2.x & 0x00FFFFFF, e2.y);
    }
    if (bkt == 0 && t == 0) row_ptr[N] = E;
}

// ---------------- layer 1 (fused with layer-2 linear) ----------------

// One wave per dst node, lane = 2 channels; node wave-uniform -> scalar s_loads.
// Tail weights staged in LDS ONCE per block (entry barrier only): zero VMEM
// and zero extra VGPR in the tail; conflict-free LDS layout (wlds[kk*64+lane]
// contiguous across lanes; h read at k=sub+kk*8 = 8 banks x 8-lane broadcast).
__global__ void k_l1_node(const int2* __restrict__ csr, const int* __restrict__ row_ptr,
                          const float* __restrict__ x, const float* __restrict__ loop_ea,
                          const float* __restrict__ Wl1, const float* __restrict__ bl1,
                          const float* __restrict__ Wr1, const float* __restrict__ br1,
                          const float* __restrict__ We1, const float* __restrict__ att1,
                          const float* __restrict__ bias1, const f32x2* __restrict__ Wtile,
                          const float* __restrict__ bl2, const float* __restrict__ br2,
                          float* __restrict__ xl2, float* __restrict__ xr2, int N) {
    __shared__ float hs[4][128];
    __shared__ f32x2 wlds[1024];
    int t = threadIdx.x;
    // preload the 8 KB weight tile (coalesced), barrier BEFORE divergent work
    #pragma unroll
    for (int i = 0; i < 4; ++i) wlds[t + i * 256] = Wtile[t + i * 256];
    __syncthreads();

    int wid = t >> 6;
    int lane = t & 63;
    int node = blockIdx.x * 4 + wid;
    if (node >= N) return;
    node = __builtin_amdgcn_readfirstlane(node);

    const f32x2* Wl1v = (const f32x2*)Wl1;
    f32x2 wl0 = Wl1v[lane],        wl1v = Wl1v[64 + lane];
    f32x2 wl2v = Wl1v[128 + lane], wl3v = Wl1v[192 + lane];
    f32x2 b2 = ((const f32x2*)bl1)[lane];
    float4 xv = *(const float4*)(x + (size_t)node * 4);
    const f32x2* Wr1v = (const f32x2*)Wr1;
    f32x2 rr = ((const f32x2*)br1)[lane];
    rr = pkfma(sp(xv.x), Wr1v[lane],       rr);
    rr = pkfma(sp(xv.y), Wr1v[64 + lane],  rr);
    rr = pkfma(sp(xv.z), Wr1v[128 + lane], rr);
    rr = pkfma(sp(xv.w), Wr1v[192 + lane], rr);
    f32x2 we2 = ((const f32x2*)We1)[lane];
    f32x2 at2 = ((const f32x2*)att1)[lane] * LOG2E;   // fold exp -> exp2
    const char* xb = (const char*)x;

    #define VL2(xs) pkfma(sp((xs).w), wl3v, pkfma(sp((xs).z), wl2v, \
                    pkfma(sp((xs).y), wl1v, pkfma(sp((xs).x), wl0, b2))))
    #define LOGIT(xs, ee, vl, aa) \
        f32x2 vl = VL2(xs); \
        float aa; \
        { f32x2 m_ = lrelu2(pkfma(sp(ee), we2, vl + rr)); \
          f32x2 q_ = m_ * at2; \
          float p_ = q_.x + q_.y; RED8(p_); aa = fexp2(p_); }

    int start = row_ptr[node];
    int deg   = row_ptr[node + 1] - start;
    const int2* crow = csr + start;

    // self-loop
    float eav = loop_ea[node];
    LOGIT(xv, eav, vls, a);
    float den = a;
    f32x2 acc = sp(a) * vls;
    int k = 0;
    for (; k + 8 <= deg; k += 8) {
        int2 q0 = crow[k],     q1 = crow[k + 1], q2 = crow[k + 2], q3 = crow[k + 3];
        int2 q4 = crow[k + 4], q5 = crow[k + 5], q6 = crow[k + 6], q7 = crow[k + 7];
        float4 y0 = *(const float4*)(xb + (unsigned)q0.x);
        float4 y1 = *(const float4*)(xb + (unsigned)q1.x);
        float4 y2 = *(const float4*)(xb + (unsigned)q2.x);
        float4 y3 = *(const float4*)(xb + (unsigned)q3.x);
        float4 y4 = *(const float4*)(xb + (unsigned)q4.x);
        float4 y5 = *(const float4*)(xb + (unsigned)q5.x);
        float4 y6 = *(const float4*)(xb + (unsigned)q6.x);
        float4 y7 = *(const float4*)(xb + (unsigned)q7.x);
        LOGIT(y0, __int_as_float(q0.y), ul0, b0);
        LOGIT(y1, __int_as_float(q1.y), ul1, b1);
        LOGIT(y2, __int_as_float(q2.y), ul2, bb2);
        LOGIT(y3, __int_as_float(q3.y), ul3, b3);
        LOGIT(y4, __int_as_float(q4.y), ul4, b4);
        LOGIT(y5, __int_as_float(q5.y), ul5, b5);
        LOGIT(y6, __int_as_float(q6.y), ul6, b6);
        LOGIT(y7, __int_as_float(q7.y), ul7, b7);
        den += ((b0 + b1) + (bb2 + b3)) + ((b4 + b5) + (b6 + b7));
        acc = pkfma(sp(b0), ul0, acc);
        acc = pkfma(sp(b1), ul1, acc);
        acc = pkfma(sp(bb2), ul2, acc);
        acc = pkfma(sp(b3), ul3, acc);
        acc = pkfma(sp(b4), ul4, acc);
        acc = pkfma(sp(b5), ul5, acc);
        acc = pkfma(sp(b6), ul6, acc);
        acc = pkfma(sp(b7), ul7, acc);
    }
    for (; k + 4 <= deg; k += 4) {
        int2 pr0 = crow[k],     pr1 = crow[k + 1];
        int2 pr2 = crow[k + 2], pr3 = crow[k + 3];
        float4 x0 = *(const float4*)(xb + (unsigned)pr0.x);
        float4 x1 = *(const float4*)(xb + (unsigned)pr1.x);
        float4 x2 = *(const float4*)(xb + (unsigned)pr2.x);
        float4 x3 = *(const float4*)(xb + (unsigned)pr3.x);
        LOGIT(x0, __int_as_float(pr0.y), vl0, a0);
        LOGIT(x1, __int_as_float(pr1.y), vl1, a1);
        LOGIT(x2, __int_as_float(pr2.y), vl2, a2);
        LOGIT(x3, __int_as_float(pr3.y), vl3, a3);
        den += (a0 + a1) + (a2 + a3);
        acc = pkfma(sp(a0), vl0, acc);
        acc = pkfma(sp(a1), vl1, acc);
        acc = pkfma(sp(a2), vl2, acc);
        acc = pkfma(sp(a3), vl3, acc);
    }
    for (; k < deg; ++k) {
        int2 pr = crow[k];
        float4 xs = *(const float4*)(xb + (unsigned)pr.x);
        LOGIT(xs, __int_as_float(pr.y), vls2, aa);
        den += aa;
        acc = pkfma(sp(aa), vls2, acc);
    }
    #undef VL2
    #undef LOGIT
    f32x2 bia = ((const f32x2*)bias1)[lane];
    f32x2 o = pkfma(acc, sp(1.0f / den), bia);
    float o0 = elu1(o.x);
    float o1 = elu1(o.y);
    // per-wave LDS slice; same-wave DS ops are in-order -> no block barrier
    *(float2*)&hs[wid][lane * 2] = make_float2(o0, o1);

    // fused layer-2 linear: zero VMEM; lane (j=lane>>3, sub=lane&7) sums
    // k = sub + kk*8 for kk=0..15 (partition over subs covers all 128 k's)
    int j = lane >> 3, sub = lane & 7;
    f32x2 a2 = {0.0f, 0.0f};
    #pragma unroll
    for (int kk = 0; kk < 16; ++kk) {
        float hk = hs[wid][sub + kk * 8];
        a2 = pkfma(sp(hk), wlds[kk * 64 + lane], a2);
    }
    RED8(a2.x);
    RED8(a2.y);
    if (sub == 0) {
        xl2[(size_t)node * 8 + j] = a2.x + bl2[j];
        xr2[(size_t)node * 8 + j] = a2.y + br2[j];
    }
}

// ---------------- layer 2 ----------------

// 8 lanes per dst node, lane = edge within group. Per-lane local accumulation;
// single deferred 9-value DPP reduce per node (sums are linear).
__global__ void k_l2_node(const int2* __restrict__ csr, const int* __restrict__ row_ptr,
                          const float* __restrict__ xl2, const float* __restrict__ xr2,
                          const float* __restrict__ loop_ea,
                          const float* __restrict__ We2, const float* __restrict__ att2,
                          const float* __restrict__ bias2, float* __restrict__ h2, int N) {
    int t = blockIdx.x * blockDim.x + threadIdx.x;
    int node = t >> 3;
    int lane = t & 7;
    if (node >= N) return;
    float4 ra = *(const float4*)(xr2 + (size_t)node * 8);
    float4 rb = *(const float4*)(xr2 + (size_t)node * 8 + 4);
    f32x2 rv0 = {ra.x, ra.y}, rv1 = {ra.z, ra.w}, rv2 = {rb.x, rb.y}, rv3 = {rb.z, rb.w};
    f32x2 we0 = ((const f32x2*)We2)[0], we1 = ((const f32x2*)We2)[1];
    f32x2 we2v = ((const f32x2*)We2)[2], we3 = ((const f32x2*)We2)[3];
    f32x2 at0 = ((const f32x2*)att2)[0] * LOG2E, at1 = ((const f32x2*)att2)[1] * LOG2E;
    f32x2 at2v = ((const f32x2*)att2)[2] * LOG2E, at3 = ((const f32x2*)att2)[3] * LOG2E;
    const char* xlb = (const char*)xl2;
    int start = row_ptr[node], deg = row_ptr[node + 1] - start;
    int total = deg + 1;          // + self loop
    float den = 0.0f;
    f32x2 ac0 = {0,0}, ac1 = {0,0}, ac2 = {0,0}, ac3 = {0,0};
    for (int base = 0; base < total; base += 8) {
        int e = base + lane;
        if (e < total) {
            const float* lp;
            float eav;
            if (e < deg) {
                int2 pr = csr[start + e];
                lp = (const float*)(xlb + 2u * (unsigned)pr.x);   // src*32 bytes
                eav = __int_as_float(pr.y);
            } else {
                lp = xl2 + (size_t)node * 8;
                eav = loop_ea[node];
            }
            float4 la = *(const float4*)lp;
            float4 lb = *(const float4*)(lp + 4);
            f32x2 l0 = {la.x, la.y}, l1 = {la.z, la.w};
            f32x2 l2 = {lb.x, lb.y}, l3 = {lb.z, lb.w};
            f32x2 ev = sp(eav);
            f32x2 q = lrelu2(pkfma(ev, we0, l0 + rv0)) * at0;
            q = pkfma(lrelu2(pkfma(ev, we1, l1 + rv1)), at1, q);
            q = pkfma(lrelu2(pkfma(ev, we2v, l2 + rv2)), at2v, q);
            q = pkfma(lrelu2(pkfma(ev, we3, l3 + rv3)), at3, q);
            float a = fexp2(q.x + q.y);
            den += a;
            f32x2 av = sp(a);
            ac0 = pkfma(av, l0, ac0);
            ac1 = pkfma(av, l1, ac1);
            ac2 = pkfma(av, l2, ac2);
            ac3 = pkfma(av, l3, ac3);
        }
    }
    // single deferred reduction across the 8-lane group
    RED8(den);
    float w0 = ac0.x, w1 = ac0.y, w2 = ac1.x, w3 = ac1.y;
    float w4 = ac2.x, w5 = ac2.y, w6 = ac3.x, w7 = ac3.y;
    RED8(w0); RED8(w1); RED8(w2); RED8(w3);
    RED8(w4); RED8(w5); RED8(w6); RED8(w7);
    if (lane == 0) {
        float inv = 1.0f / den;
        float o[8] = {w0, w1, w2, w3, w4, w5, w6, w7};
        #pragma unroll
        for (int cc = 0; cc < 8; ++cc) {
            float v = fmaf(o[cc], inv, bias2[cc]);
            o[cc] = elu1(v);
        }
        *(float4*)(h2 + (size_t)node * 8)     = make_float4(o[0], o[1], o[2], o[3]);
        *(float4*)(h2 + (size_t)node * 8 + 4) = make_float4(o[4], o[5], o[6], o[7]);
    }
}

// One block per graph; batch is sorted -> binary-search the segment.
__global__ void k_pool(const float* __restrict__ h2, const int* __restrict__ batch,
                       const float* __restrict__ W3, const float* __restrict__ b3,
                       float* __restrict__ out, int N) {
    int g = blockIdx.x;
    int lo = 0, hi = N;
    while (lo < hi) { int mid = (lo + hi) >> 1; if (batch[mid] < g) lo = mid + 1; else hi = mid; }
    int start = lo;
    int lo2 = start, hi2 = N;
    while (lo2 < hi2) { int mid = (lo2 + hi2) >> 1; if (batch[mid] < g + 1) lo2 = mid + 1; else hi2 = mid; }
    int end = lo2;
    int cnt = end - start;
    int t = threadIdx.x;
    int c = t & 7, rg = t >> 3;
    float s = 0.0f;
    for (int i = start + rg; i < end; i += 32) s += h2[(size_t)i * 8 + c];
    __shared__ float sm[256];
    sm[t] = s;
    __syncthreads();
    #pragma unroll
    for (int off = 16; off >= 1; off >>= 1) {
        if (rg < off) sm[t] += sm[t + off * 8];
        __syncthreads();
    }
    if (t == 0) {
        float inv = 1.0f / fmaxf((float)cnt, 1.0f);
        float acc = b3[0];
        #pragma unroll
        for (int cc = 0; cc < 8; ++cc) acc = fmaf(sm[cc] * inv, W3[cc], acc);
        out[g] = acc;
    }
}

extern "C" void kernel_launch(void* const* d_in, const int* in_sizes, int n_in,
                              void* d_out, int out_size, void* d_ws, size_t ws_size,
                              hipStream_t stream) {
    const float* x     = (const float*)d_in[0];
    const int*   ei    = (const int*)d_in[1];
    const float* ea    = (const float*)d_in[2];
    const int*   batch = (const int*)d_in[3];
    const float* Wl1 = (const float*)d_in[4];
    const float* bl1 = (const float*)d_in[5];
    const float* Wr1 = (const float*)d_in[6];
    const float* br1 = (const float*)d_in[7];
    const float* We1 = (const float*)d_in[8];
    const float* att1 = (const float*)d_in[9];
    const float* bias1 = (const float*)d_in[10];
    const float* Wl2 = (const float*)d_in[11];
    const float* bl2 = (const float*)d_in[12];
    const float* Wr2 = (const float*)d_in[13];
    const float* br2 = (const float*)d_in[14];
    const float* We2 = (const float*)d_in[15];
    const float* att2 = (const float*)d_in[16];
    const float* bias2 = (const float*)d_in[17];
    const float* W3 = (const float*)d_in[18];
    const float* b3 = (const float*)d_in[19];

    const int N  = in_sizes[0] / 4;
    const int E  = in_sizes[1] / 2;
    const int G  = out_size;
    const int* src = ei;
    const int* dst = ei + E;

    const int NBK = (N + 255) >> 8;                      // buckets of 256 nodes, <= 256
    const int NCH = 256;                                 // edge chunks
    const int CE  = (((E + NCH - 1) / NCH) + 3) & ~3;    // edges per chunk, x4-aligned
    const int L   = NBK * 256;                           // count-matrix length

    #define ALIGN4(v) (((v) + 3) & ~3)
    int* w = (int*)d_ws;
    int* gofs     = w; w += ALIGN4(L + 1);
    int* blocksum = w; w += 256;
    int* row_ptr  = w; w += ALIGN4(N + 1);
    float* loop_ea = (float*)w; w += ALIGN4(N);
    float* xl2 = (float*)w; w += (size_t)N * 8;
    float* xr2 = (float*)w; w += (size_t)N * 8;
    float* h2  = (float*)w; w += (size_t)N * 8;
    float2* Wtile = (float2*)w; w += 2048;
    int2* tmp = (int2*)w; w += (size_t)E * 2;
    int2* csr = (int2*)w; w += (size_t)E * 2;
    #undef ALIGN4

    // CSR build: two-level counting sort (block-offset add folded into consumers)
    k_bcnt<<<NCH, 1024, 0, stream>>>(dst, gofs, E, CE, NBK);
    k_scan1<<<NBK, 256, 0, stream>>>(gofs, gofs, blocksum, L);
    k_scan2<<<1, 256, 0, stream>>>(blocksum, NBK, Wl2, Wr2, Wtile);
    k_part<<<NCH, 1024, 0, stream>>>(src, dst, ea, gofs, blocksum, tmp, E, CE, NBK);
    k_fsort<<<NBK, 1024, 0, stream>>>(tmp, gofs, blocksum, csr, row_ptr, loop_ea, N, E, NBK);

    // layer 1 (+ fused layer-2 linear; h1 never touches HBM)
    k_l1_node<<<(N + 3) / 4, 256, 0, stream>>>(csr, row_ptr, x, loop_ea,
                                               Wl1, bl1, Wr1, br1, We1, att1, bias1,
                                               (const f32x2*)Wtile, bl2, br2, xl2, xr2, N);
    // layer 2
    k_l2_node<<<((size_t)N * 8 + 255) / 256, 256, 0, stream>>>(csr, row_ptr, xl2, xr2,
                                                               loop_ea, We2, att2, bias2, h2, N);
    // pool + final linear
    k_pool<<<G, 256, 0, stream>>>(h2, batch, W3, b3, (float*)d_out, N);
}

// Round 22
// 100.124 us; speedup vs baseline: 1.6686x; 1.0026x over previous
//
#include <hip/hip_runtime.h>
#include <math.h>

#define LOG2E 1.44269504088896340736f

typedef float f32x2 __attribute__((ext_vector_type(2)));
__device__ __forceinline__ f32x2 pkfma(f32x2 a, f32x2 b, f32x2 c) {
    return __builtin_elementwise_fma(a, b, c);
}
__device__ __forceinline__ f32x2 sp(float s) { f32x2 v = {s, s}; return v; }
__device__ __forceinline__ f32x2 lrelu2(f32x2 m) {
    return __builtin_elementwise_max(m, 0.2f * m);
}
// raw v_exp_f32 (single inst); logits/activations are O(1) so denorm path irrelevant
__device__ __forceinline__ float fexp2(float x) {
    float r;
    asm("v_exp_f32 %0, %1" : "=v"(r) : "v"(x));
    return r;
}
// elu via raw exp2: v>0 ? v : e^v-1
__device__ __forceinline__ float elu1(float v) {
    return v > 0.0f ? v : fexp2(v * LOG2E) - 1.0f;
}

// butterfly add via DPP (pure VALU, no LDS): xor1=quad_perm[1,0,3,2],
// xor2=quad_perm[2,3,0,1], 8-lane mirror = row_half_mirror
#define DPPADD(p, ctrl) \
    p += __int_as_float(__builtin_amdgcn_mov_dpp(__float_as_int(p), ctrl, 0xF, 0xF, true))
#define RED8(p) do { DPPADD(p, 0xB1); DPPADD(p, 0x4E); DPPADD(p, 0x141); } while (0)

// ---------------- CSR build: two-level counting sort (no global atomics) ----

__global__ void k_bcnt(const int* __restrict__ dst, int* __restrict__ cntmat,
                       int E, int CE, int NBK) {
    __shared__ int cnt[256];
    int t = threadIdx.x;
    if (t < 256) cnt[t] = 0;
    __syncthreads();
    int c = blockIdx.x;
    int lo = c * CE, hi = min(E, lo + CE);
    int len = hi - lo; if (len < 0) len = 0;
    int len4 = len & ~3;
    for (int o = t * 4; o < len4; o += 4096) {
        int4 d4 = *(const int4*)(dst + lo + o);
        atomicAdd(&cnt[d4.x >> 8], 1);
        atomicAdd(&cnt[d4.y >> 8], 1);
        atomicAdd(&cnt[d4.z >> 8], 1);
        atomicAdd(&cnt[d4.w >> 8], 1);
    }
    for (int o = len4 + t; o < len; o += 1024)
        atomicAdd(&cnt[dst[lo + o] >> 8], 1);
    __syncthreads();
    if (t < NBK) cntmat[t * 256 + c] = cnt[t];
}

__global__ void k_scan1(const int* __restrict__ in, int* __restrict__ out,
                        int* __restrict__ blocksum, int L) {
    __shared__ int sm[256];
    int t = threadIdx.x;
    int i = blockIdx.x * 256 + t;
    int v = (i < L) ? in[i] : 0;
    sm[t] = v;
    __syncthreads();
    #pragma unroll
    for (int off = 1; off < 256; off <<= 1) {
        int add = (t >= off) ? sm[t - off] : 0;
        __syncthreads();
        sm[t] += add;
        __syncthreads();
    }
    if (i < L) out[i] = sm[t] - v;   // exclusive (block-local)
    if (t == 255) blocksum[blockIdx.x] = sm[255];
}

// scan block totals in place; idle threads build the tail weight table in the
// LDS-friendly layout: Wtile[kk*64 + l] = (Wl2[k][j], Wr2[k][j]) with
// j = l>>3, k = (l&7) + kk*8  (kk in [0,16), l in [0,64))
__global__ void k_scan2(int* __restrict__ blocksum, int nb,
                        const float* __restrict__ Wl2, const float* __restrict__ Wr2,
                        float2* __restrict__ Wtile) {
    __shared__ int sm[256];
    int t = threadIdx.x;
    int v = (t < nb) ? blocksum[t] : 0;
    sm[t] = v;
    __syncthreads();
    #pragma unroll
    for (int off = 1; off < 256; off <<= 1) {
        int add = (t >= off) ? sm[t - off] : 0;
        __syncthreads();
        sm[t] += add;
        __syncthreads();
    }
    if (t < nb) blocksum[t] = sm[t] - v;
    #pragma unroll
    for (int i = 0; i < 4; ++i) {
        int idx = t + i * 256;
        int kk = idx >> 6, l = idx & 63;
        int j = l >> 3, sub = l & 7;
        int k = sub + kk * 8;
        Wtile[idx] = make_float2(Wl2[k * 8 + j], Wr2[k * 8 + j]);
    }
}

__global__ void k_part(const int* __restrict__ src, const int* __restrict__ dst,
                       const float* __restrict__ ea, const int* __restrict__ gofs,
                       const int* __restrict__ blocksum,
                       int2* __restrict__ tmp, int E, int CE, int NBK) {
    __shared__ int cur[256];
    int t = threadIdx.x;
    int c = blockIdx.x;
    if (t < NBK) cur[t] = gofs[t * 256 + c] + blocksum[t];
    __syncthreads();
    int lo = c * CE, hi = min(E, lo + CE);
    int len = hi - lo; if (len < 0) len = 0;
    int len4 = len & ~3;
    for (int o = t * 4; o < len4; o += 4096) {
        int e = lo + o;
        int4 s4 = *(const int4*)(src + e);
        int4 d4 = *(const int4*)(dst + e);
        float4 a4 = *(const float4*)(ea + e);
        int p0 = atomicAdd(&cur[d4.x >> 8], 1);
        int p1 = atomicAdd(&cur[d4.y >> 8], 1);
        int p2 = atomicAdd(&cur[d4.z >> 8], 1);
        int p3 = atomicAdd(&cur[d4.w >> 8], 1);
        tmp[p0] = make_int2(((d4.x & 255) << 24) | (s4.x << 4), __float_as_int(a4.x));
        tmp[p1] = make_int2(((d4.y & 255) << 24) | (s4.y << 4), __float_as_int(a4.y));
        tmp[p2] = make_int2(((d4.z & 255) << 24) | (s4.z << 4), __float_as_int(a4.z));
        tmp[p3] = make_int2(((d4.w & 255) << 24) | (s4.w << 4), __float_as_int(a4.w));
    }
    for (int o = len4 + t; o < len; o += 1024) {
        int e = lo + o;
        int d = dst[e];
        int pos = atomicAdd(&cur[d >> 8], 1);
        tmp[pos] = make_int2(((d & 255) << 24) | (src[e] << 4), __float_as_int(ea[e]));
    }
}

// fine sort within bucket (loop_ea removed: node kernels compute ea-sums inline)
__global__ void k_fsort(const int2* __restrict__ tmp, const int* __restrict__ gofs,
                        const int* __restrict__ blocksum,
                        int2* __restrict__ csr, int* __restrict__ row_ptr,
                        int N, int E, int NBK) {
    __shared__ int lcnt[256], lofs[256], lcur[256];
    int bkt = blockIdx.x;
    int t = threadIdx.x;
    int base = gofs[bkt * 256] + blocksum[bkt];
    int endv = (bkt == NBK - 1) ? E : (gofs[(bkt + 1) * 256] + blocksum[bkt + 1]);
    int cnt = endv - base;
    if (t < 256) lcnt[t] = 0;
    __syncthreads();
    for (int i = t; i < cnt; i += 1024) {
        int2 e2 = tmp[base + i];
        atomicAdd(&lcnt[(unsigned)e2.x >> 24], 1);
    }
    __syncthreads();
    int v = (t < 256) ? lcnt[t] : 0;
    if (t < 256) lofs[t] = v;
    __syncthreads();
    #pragma unroll
    for (int off = 1; off < 256; off <<= 1) {
        int add = (t >= off && t < 256) ? lofs[t - off] : 0;
        __syncthreads();
        if (t < 256) lofs[t] += add;
        __syncthreads();
    }
    if (t < 256) {
        int excl = lofs[t] - v;
        int nlo = bkt << 8;
        if (nlo + t < N) row_ptr[nlo + t] = base + excl;
        lcur[t] = base + excl;
    }
    __syncthreads();
    for (int i = t; i < cnt; i += 1024) {
        int2 e2 = tmp[base + i];
        int dl = (unsigned)e2.x >> 24;
        int pos = atomicAdd(&lcur[dl], 1);
        csr[pos] = make_int2(e2.x & 0x00FFFFFF, e2.y);
    }
    if (bkt == 0 && t == 0) row_ptr[N] = E;
}

// ---------------- layer 1 (fused with layer-2 linear) ----------------

// One wave per dst node, lane = 2 channels; node wave-uniform -> scalar s_loads.
// Edge loop software-pipelined: csr entries for iteration i+1 prefetched before
// iteration i's compute (removes one serial s_load wait per 8 edges).
// ea-sum accumulated inline; self-loop processed LAST with eav = easum/deg.
// Tail weights staged in LDS once per block (entry barrier only).
__global__ void k_l1_node(const int2* __restrict__ csr, const int* __restrict__ row_ptr,
                          const float* __restrict__ x,
                          const float* __restrict__ Wl1, const float* __restrict__ bl1,
                          const float* __restrict__ Wr1, const float* __restrict__ br1,
                          const float* __restrict__ We1, const float* __restrict__ att1,
                          const float* __restrict__ bias1, const f32x2* __restrict__ Wtile,
                          const float* __restrict__ bl2, const float* __restrict__ br2,
                          float* __restrict__ xl2, float* __restrict__ xr2, int N) {
    __shared__ float hs[4][128];
    __shared__ f32x2 wlds[1024];
    int t = threadIdx.x;
    // preload the 8 KB weight tile (coalesced), barrier BEFORE divergent work
    #pragma unroll
    for (int i = 0; i < 4; ++i) wlds[t + i * 256] = Wtile[t + i * 256];
    __syncthreads();

    int wid = t >> 6;
    int lane = t & 63;
    int node = blockIdx.x * 4 + wid;
    if (node >= N) return;
    node = __builtin_amdgcn_readfirstlane(node);

    const f32x2* Wl1v = (const f32x2*)Wl1;
    f32x2 wl0 = Wl1v[lane],        wl1v = Wl1v[64 + lane];
    f32x2 wl2v = Wl1v[128 + lane], wl3v = Wl1v[192 + lane];
    f32x2 b2 = ((const f32x2*)bl1)[lane];
    float4 xv = *(const float4*)(x + (size_t)node * 4);
    const f32x2* Wr1v = (const f32x2*)Wr1;
    f32x2 rr = ((const f32x2*)br1)[lane];
    rr = pkfma(sp(xv.x), Wr1v[lane],       rr);
    rr = pkfma(sp(xv.y), Wr1v[64 + lane],  rr);
    rr = pkfma(sp(xv.z), Wr1v[128 + lane], rr);
    rr = pkfma(sp(xv.w), Wr1v[192 + lane], rr);
    f32x2 we2 = ((const f32x2*)We1)[lane];
    f32x2 at2 = ((const f32x2*)att1)[lane] * LOG2E;   // fold exp -> exp2
    const char* xb = (const char*)x;

    #define VL2(xs) pkfma(sp((xs).w), wl3v, pkfma(sp((xs).z), wl2v, \
                    pkfma(sp((xs).y), wl1v, pkfma(sp((xs).x), wl0, b2))))
    #define LOGIT(xs, ee, vl, aa) \
        f32x2 vl = VL2(xs); \
        float aa; \
        { f32x2 m_ = lrelu2(pkfma(sp(ee), we2, vl + rr)); \
          f32x2 q_ = m_ * at2; \
          float p_ = q_.x + q_.y; RED8(p_); aa = fexp2(p_); }

    int start = row_ptr[node];
    int deg   = row_ptr[node + 1] - start;
    const int2* crow = csr + start;

    float den = 0.0f;
    f32x2 acc = {0.0f, 0.0f};
    float easum = 0.0f;
    int k = 0;
    if (deg >= 8) {
        int2 q0 = crow[0], q1 = crow[1], q2 = crow[2], q3 = crow[3];
        int2 q4 = crow[4], q5 = crow[5], q6 = crow[6], q7 = crow[7];
        for (; k + 16 <= deg; k += 8) {
            float4 y0 = *(const float4*)(xb + (unsigned)q0.x);
            float4 y1 = *(const float4*)(xb + (unsigned)q1.x);
            float4 y2 = *(const float4*)(xb + (unsigned)q2.x);
            float4 y3 = *(const float4*)(xb + (unsigned)q3.x);
            float4 y4 = *(const float4*)(xb + (unsigned)q4.x);
            float4 y5 = *(const float4*)(xb + (unsigned)q5.x);
            float4 y6 = *(const float4*)(xb + (unsigned)q6.x);
            float4 y7 = *(const float4*)(xb + (unsigned)q7.x);
            // prefetch next iteration's csr entries before compute
            int2 n0 = crow[k + 8],  n1 = crow[k + 9];
            int2 n2 = crow[k + 10], n3 = crow[k + 11];
            int2 n4 = crow[k + 12], n5 = crow[k + 13];
            int2 n6 = crow[k + 14], n7 = crow[k + 15];
            float e0 = __int_as_float(q0.y), e1 = __int_as_float(q1.y);
            float e2 = __int_as_float(q2.y), e3 = __int_as_float(q3.y);
            float e4 = __int_as_float(q4.y), e5 = __int_as_float(q5.y);
            float e6 = __int_as_float(q6.y), e7 = __int_as_float(q7.y);
            easum += ((e0 + e1) + (e2 + e3)) + ((e4 + e5) + (e6 + e7));
            LOGIT(y0, e0, ul0, b0);
            LOGIT(y1, e1, ul1, b1);
            LOGIT(y2, e2, ul2, bb2);
            LOGIT(y3, e3, ul3, b3);
            LOGIT(y4, e4, ul4, b4);
            LOGIT(y5, e5, ul5, b5);
            LOGIT(y6, e6, ul6, b6);
            LOGIT(y7, e7, ul7, b7);
            den += ((b0 + b1) + (bb2 + b3)) + ((b4 + b5) + (b6 + b7));
            acc = pkfma(sp(b0), ul0, acc);
            acc = pkfma(sp(b1), ul1, acc);
            acc = pkfma(sp(bb2), ul2, acc);
            acc = pkfma(sp(b3), ul3, acc);
            acc = pkfma(sp(b4), ul4, acc);
            acc = pkfma(sp(b5), ul5, acc);
            acc = pkfma(sp(b6), ul6, acc);
            acc = pkfma(sp(b7), ul7, acc);
            q0 = n0; q1 = n1; q2 = n2; q3 = n3;
            q4 = n4; q5 = n5; q6 = n6; q7 = n7;
        }
        {   // final full block of 8 using current q registers
            float4 y0 = *(const float4*)(xb + (unsigned)q0.x);
            float4 y1 = *(const float4*)(xb + (unsigned)q1.x);
            float4 y2 = *(const float4*)(xb + (unsigned)q2.x);
            float4 y3 = *(const float4*)(xb + (unsigned)q3.x);
            float4 y4 = *(const float4*)(xb + (unsigned)q4.x);
            float4 y5 = *(const float4*)(xb + (unsigned)q5.x);
            float4 y6 = *(const float4*)(xb + (unsigned)q6.x);
            float4 y7 = *(const float4*)(xb + (unsigned)q7.x);
            float e0 = __int_as_float(q0.y), e1 = __int_as_float(q1.y);
            float e2 = __int_as_float(q2.y), e3 = __int_as_float(q3.y);
            float e4 = __int_as_float(q4.y), e5 = __int_as_float(q5.y);
            float e6 = __int_as_float(q6.y), e7 = __int_as_float(q7.y);
            easum += ((e0 + e1) + (e2 + e3)) + ((e4 + e5) + (e6 + e7));
            LOGIT(y0, e0, ul0, b0);
            LOGIT(y1, e1, ul1, b1);
            LOGIT(y2, e2, ul2, bb2);
            LOGIT(y3, e3, ul3, b3);
            LOGIT(y4, e4, ul4, b4);
            LOGIT(y5, e5, ul5, b5);
            LOGIT(y6, e6, ul6, b6);
            LOGIT(y7, e7, ul7, b7);
            den += ((b0 + b1) + (bb2 + b3)) + ((b4 + b5) + (b6 + b7));
            acc = pkfma(sp(b0), ul0, acc);
            acc = pkfma(sp(b1), ul1, acc);
            acc = pkfma(sp(bb2), ul2, acc);
            acc = pkfma(sp(b3), ul3, acc);
            acc = pkfma(sp(b4), ul4, acc);
            acc = pkfma(sp(b5), ul5, acc);
            acc = pkfma(sp(b6), ul6, acc);
            acc = pkfma(sp(b7), ul7, acc);
            k += 8;
        }
    }
    for (; k < deg; ++k) {
        int2 pr = crow[k];
        float ee = __int_as_float(pr.y);
        float4 xs = *(const float4*)(xb + (unsigned)pr.x);
        easum += ee;
        LOGIT(xs, ee, vls2, aa);
        den += aa;
        acc = pkfma(sp(aa), vls2, acc);
    }
    // self-loop LAST: eav = mean of incoming ea (PyG fill_value='mean')
    {
        float eav = easum / fmaxf((float)deg, 1.0f);
        LOGIT(xv, eav, vls, a);
        den += a;
        acc = pkfma(sp(a), vls, acc);
    }
    #undef VL2
    #undef LOGIT
    f32x2 bia = ((const f32x2*)bias1)[lane];
    f32x2 o = pkfma(acc, sp(1.0f / den), bia);
    float o0 = elu1(o.x);
    float o1 = elu1(o.y);
    // per-wave LDS slice; same-wave DS ops are in-order -> no block barrier
    *(float2*)&hs[wid][lane * 2] = make_float2(o0, o1);

    // fused layer-2 linear: zero VMEM; lane (j=lane>>3, sub=lane&7) sums
    // k = sub + kk*8 for kk=0..15 (partition over subs covers all 128 k's)
    int j = lane >> 3, sub = lane & 7;
    f32x2 a2 = {0.0f, 0.0f};
    #pragma unroll
    for (int kk = 0; kk < 16; ++kk) {
        float hk = hs[wid][sub + kk * 8];
        a2 = pkfma(sp(hk), wlds[kk * 64 + lane], a2);
    }
    RED8(a2.x);
    RED8(a2.y);
    if (sub == 0) {
        xl2[(size_t)node * 8 + j] = a2.x + bl2[j];
        xr2[(size_t)node * 8 + j] = a2.y + br2[j];
    }
}

// ---------------- layer 2 ----------------

// 8 lanes per dst node, lane = edge within group. Per-lane local accumulation;
// deferred 10-value DPP reduce; self-loop handled post-reduction by lane 0.
__global__ void k_l2_node(const int2* __restrict__ csr, const int* __restrict__ row_ptr,
                          const float* __restrict__ xl2, const float* __restrict__ xr2,
                          const float* __restrict__ We2, const float* __restrict__ att2,
                          const float* __restrict__ bias2, float* __restrict__ h2, int N) {
    int t = blockIdx.x * blockDim.x + threadIdx.x;
    int node = t >> 3;
    int lane = t & 7;
    if (node >= N) return;
    float4 ra = *(const float4*)(xr2 + (size_t)node * 8);
    float4 rb = *(const float4*)(xr2 + (size_t)node * 8 + 4);
    f32x2 rv0 = {ra.x, ra.y}, rv1 = {ra.z, ra.w}, rv2 = {rb.x, rb.y}, rv3 = {rb.z, rb.w};
    f32x2 we0 = ((const f32x2*)We2)[0], we1 = ((const f32x2*)We2)[1];
    f32x2 we2v = ((const f32x2*)We2)[2], we3 = ((const f32x2*)We2)[3];
    f32x2 at0 = ((const f32x2*)att2)[0] * LOG2E, at1 = ((const f32x2*)att2)[1] * LOG2E;
    f32x2 at2v = ((const f32x2*)att2)[2] * LOG2E, at3 = ((const f32x2*)att2)[3] * LOG2E;
    const char* xlb = (const char*)xl2;
    int start = row_ptr[node], deg = row_ptr[node + 1] - start;
    float den = 0.0f, easum = 0.0f;
    f32x2 ac0 = {0,0}, ac1 = {0,0}, ac2 = {0,0}, ac3 = {0,0};
    for (int base = 0; base < deg; base += 8) {
        int e = base + lane;
        if (e < deg) {
            int2 pr = csr[start + e];
            const float* lp = (const float*)(xlb + 2u * (unsigned)pr.x);  // src*32 bytes
            float eav = __int_as_float(pr.y);
            easum += eav;
            float4 la = *(const float4*)lp;
            float4 lb = *(const float4*)(lp + 4);
            f32x2 l0 = {la.x, la.y}, l1 = {la.z, la.w};
            f32x2 l2 = {lb.x, lb.y}, l3 = {lb.z, lb.w};
            f32x2 ev = sp(eav);
            f32x2 q = lrelu2(pkfma(ev, we0, l0 + rv0)) * at0;
            q = pkfma(lrelu2(pkfma(ev, we1, l1 + rv1)), at1, q);
            q = pkfma(lrelu2(pkfma(ev, we2v, l2 + rv2)), at2v, q);
            q = pkfma(lrelu2(pkfma(ev, we3, l3 + rv3)), at3, q);
            float a = fexp2(q.x + q.y);
            den += a;
            f32x2 av = sp(a);
            ac0 = pkfma(av, l0, ac0);
            ac1 = pkfma(av, l1, ac1);
            ac2 = pkfma(av, l2, ac2);
            ac3 = pkfma(av, l3, ac3);
        }
    }
    // deferred reduction across the 8-lane group
    RED8(den);
    RED8(easum);
    float w0 = ac0.x, w1 = ac0.y, w2 = ac1.x, w3 = ac1.y;
    float w4 = ac2.x, w5 = ac2.y, w6 = ac3.x, w7 = ac3.y;
    RED8(w0); RED8(w1); RED8(w2); RED8(w3);
    RED8(w4); RED8(w5); RED8(w6); RED8(w7);
    if (lane == 0) {
        // self-loop: eav = mean of incoming ea
        float eav = easum / fmaxf((float)deg, 1.0f);
        const float* lp = xl2 + (size_t)node * 8;
        float4 la = *(const float4*)lp;
        float4 lb = *(const float4*)(lp + 4);
        f32x2 l0 = {la.x, la.y}, l1 = {la.z, la.w};
        f32x2 l2 = {lb.x, lb.y}, l3 = {lb.z, lb.w};
        f32x2 ev = sp(eav);
        f32x2 q = lrelu2(pkfma(ev, we0, l0 + rv0)) * at0;
        q = pkfma(lrelu2(pkfma(ev, we1, l1 + rv1)), at1, q);
        q = pkfma(lrelu2(pkfma(ev, we2v, l2 + rv2)), at2v, q);
        q = pkfma(lrelu2(pkfma(ev, we3, l3 + rv3)), at3, q);
        float a = fexp2(q.x + q.y);
        den += a;
        w0 = fmaf(a, la.x, w0); w1 = fmaf(a, la.y, w1);
        w2 = fmaf(a, la.z, w2); w3 = fmaf(a, la.w, w3);
        w4 = fmaf(a, lb.x, w4); w5 = fmaf(a, lb.y, w5);
        w6 = fmaf(a, lb.z, w6); w7 = fmaf(a, lb.w, w7);
        float inv = 1.0f / den;
        float o[8] = {w0, w1, w2, w3, w4, w5, w6, w7};
        #pragma unroll
        for (int cc = 0; cc < 8; ++cc) {
            float v = fmaf(o[cc], inv, bias2[cc]);
            o[cc] = elu1(v);
        }
        *(float4*)(h2 + (size_t)node * 8)     = make_float4(o[0], o[1], o[2], o[3]);
        *(float4*)(h2 + (size_t)node * 8 + 4) = make_float4(o[4], o[5], o[6], o[7]);
    }
}

// One block per graph; batch is sorted -> binary-search the segment.
__global__ void k_pool(const float* __restrict__ h2, const int* __restrict__ batch,
                       const float* __restrict__ W3, const float* __restrict__ b3,
                       float* __restrict__ out, int N) {
    int g = blockIdx.x;
    int lo = 0, hi = N;
    while (lo < hi) { int mid = (lo + hi) >> 1; if (batch[mid] < g) lo = mid + 1; else hi = mid; }
    int start = lo;
    int lo2 = start, hi2 = N;
    while (lo2 < hi2) { int mid = (lo2 + hi2) >> 1; if (batch[mid] < g + 1) lo2 = mid + 1; else hi2 = mid; }
    int end = lo2;
    int cnt = end - start;
    int t = threadIdx.x;
    int c = t & 7, rg = t >> 3;
    float s = 0.0f;
    for (int i = start + rg; i < end; i += 32) s += h2[(size_t)i * 8 + c];
    __shared__ float sm[256];
    sm[t] = s;
    __syncthreads();
    #pragma unroll
    for (int off = 16; off >= 1; off >>= 1) {
        if (rg < off) sm[t] += sm[t + off * 8];
        __syncthreads();
    }
    if (t == 0) {
        float inv = 1.0f / fmaxf((float)cnt, 1.0f);
        float acc = b3[0];
        #pragma unroll
        for (int cc = 0; cc < 8; ++cc) acc = fmaf(sm[cc] * inv, W3[cc], acc);
        out[g] = acc;
    }
}

extern "C" void kernel_launch(void* const* d_in, const int* in_sizes, int n_in,
                              void* d_out, int out_size, void* d_ws, size_t ws_size,
                              hipStream_t stream) {
    const float* x     = (const float*)d_in[0];
    const int*   ei    = (const int*)d_in[1];
    const float* ea    = (const float*)d_in[2];
    const int*   batch = (const int*)d_in[3];
    const float* Wl1 = (const float*)d_in[4];
    const float* bl1 = (const float*)d_in[5];
    const float* Wr1 = (const float*)d_in[6];
    const float* br1 = (const float*)d_in[7];
    const float* We1 = (const float*)d_in[8];
    const float* att1 = (const float*)d_in[9];
    const float* bias1 = (const float*)d_in[10];
    const float* Wl2 = (const float*)d_in[11];
    const float* bl2 = (const float*)d_in[12];
    const float* Wr2 = (const float*)d_in[13];
    const float* br2 = (const float*)d_in[14];
    const float* We2 = (const float*)d_in[15];
    const float* att2 = (const float*)d_in[16];
    const float* bias2 = (const float*)d_in[17];
    const float* W3 = (const float*)d_in[18];
    const float* b3 = (const float*)d_in[19];

    const int N  = in_sizes[0] / 4;
    const int E  = in_sizes[1] / 2;
    const int G  = out_size;
    const int* src = ei;
    const int* dst = ei + E;

    const int NBK = (N + 255) >> 8;                      // buckets of 256 nodes, <= 256
    const int NCH = 256;                                 // edge chunks
    const int CE  = (((E + NCH - 1) / NCH) + 3) & ~3;    // edges per chunk, x4-aligned
    const int L   = NBK * 256;                           // count-matrix length

    #define ALIGN4(v) (((v) + 3) & ~3)
    int* w = (int*)d_ws;
    int* gofs     = w; w += ALIGN4(L + 1);
    int* blocksum = w; w += 256;
    int* row_ptr  = w; w += ALIGN4(N + 1);
    float* xl2 = (float*)w; w += (size_t)N * 8;
    float* xr2 = (float*)w; w += (size_t)N * 8;
    float* h2  = (float*)w; w += (size_t)N * 8;
    float2* Wtile = (float2*)w; w += 2048;
    int2* tmp = (int2*)w; w += (size_t)E * 2;
    int2* csr = (int2*)w; w += (size_t)E * 2;
    #undef ALIGN4

    // CSR build: two-level counting sort (block-offset add folded into consumers)
    k_bcnt<<<NCH, 1024, 0, stream>>>(dst, gofs, E, CE, NBK);
    k_scan1<<<NBK, 256, 0, stream>>>(gofs, gofs, blocksum, L);
    k_scan2<<<1, 256, 0, stream>>>(blocksum, NBK, Wl2, Wr2, Wtile);
    k_part<<<NCH, 1024, 0, stream>>>(src, dst, ea, gofs, blocksum, tmp, E, CE, NBK);
    k_fsort<<<NBK, 1024, 0, stream>>>(tmp, gofs, blocksum, csr, row_ptr, N, E, NBK);

    // layer 1 (+ fused layer-2 linear; h1 never touches HBM)
    k_l1_node<<<(N + 3) / 4, 256, 0, stream>>>(csr, row_ptr, x,
                                               Wl1, bl1, Wr1, br1, We1, att1, bias1,
                                               (const f32x2*)Wtile, bl2, br2, xl2, xr2, N);
    // layer 2
    k_l2_node<<<((size_t)N * 8 + 255) / 256, 256, 0, stream>>>(csr, row_ptr, xl2, xr2,
                                                               We2, att2, bias2, h2, N);
    // pool + final linear
    k_pool<<<G, 256, 0, stream>>>(h2, batch, W3, b3, (float*)d_out, N);
}

// Round 23
// 99.438 us; speedup vs baseline: 1.6802x; 1.0069x over previous
//
#include <hip/hip_runtime.h>
#include <math.h>

#define LOG2E 1.44269504088896340736f

typedef float f32x2 __attribute__((ext_vector_type(2)));
__device__ __forceinline__ f32x2 pkfma(f32x2 a, f32x2 b, f32x2 c) {
    return __builtin_elementwise_fma(a, b, c);
}
__device__ __forceinline__ f32x2 sp(float s) { f32x2 v = {s, s}; return v; }
__device__ __forceinline__ f32x2 lrelu2(f32x2 m) {
    return __builtin_elementwise_max(m, 0.2f * m);
}
// raw v_exp_f32 (single inst); logits/activations are O(1) so denorm path irrelevant
__device__ __forceinline__ float fexp2(float x) {
    float r;
    asm("v_exp_f32 %0, %1" : "=v"(r) : "v"(x));
    return r;
}
// elu via raw exp2: v>0 ? v : e^v-1
__device__ __forceinline__ float elu1(float v) {
    return v > 0.0f ? v : fexp2(v * LOG2E) - 1.0f;
}

// butterfly add via DPP (pure VALU, no LDS): xor1=quad_perm[1,0,3,2],
// xor2=quad_perm[2,3,0,1], 8-lane mirror = row_half_mirror
#define DPPADD(p, ctrl) \
    p += __int_as_float(__builtin_amdgcn_mov_dpp(__float_as_int(p), ctrl, 0xF, 0xF, true))
#define RED8(p) do { DPPADD(p, 0xB1); DPPADD(p, 0x4E); DPPADD(p, 0x141); } while (0)

// ---------------- CSR build: two-level counting sort (no global atomics) ----

__global__ void k_bcnt(const int* __restrict__ dst, int* __restrict__ cntmat,
                       int E, int CE, int NBK) {
    __shared__ int cnt[256];
    int t = threadIdx.x;
    if (t < 256) cnt[t] = 0;
    __syncthreads();
    int c = blockIdx.x;
    int lo = c * CE, hi = min(E, lo + CE);
    int len = hi - lo; if (len < 0) len = 0;
    int len4 = len & ~3;
    for (int o = t * 4; o < len4; o += 4096) {
        int4 d4 = *(const int4*)(dst + lo + o);
        atomicAdd(&cnt[d4.x >> 8], 1);
        atomicAdd(&cnt[d4.y >> 8], 1);
        atomicAdd(&cnt[d4.z >> 8], 1);
        atomicAdd(&cnt[d4.w >> 8], 1);
    }
    for (int o = len4 + t; o < len; o += 1024)
        atomicAdd(&cnt[dst[lo + o] >> 8], 1);
    __syncthreads();
    if (t < NBK) cntmat[t * 256 + c] = cnt[t];
}

__global__ void k_scan1(const int* __restrict__ in, int* __restrict__ out,
                        int* __restrict__ blocksum, int L) {
    __shared__ int sm[256];
    int t = threadIdx.x;
    int i = blockIdx.x * 256 + t;
    int v = (i < L) ? in[i] : 0;
    sm[t] = v;
    __syncthreads();
    #pragma unroll
    for (int off = 1; off < 256; off <<= 1) {
        int add = (t >= off) ? sm[t - off] : 0;
        __syncthreads();
        sm[t] += add;
        __syncthreads();
    }
    if (i < L) out[i] = sm[t] - v;   // exclusive (block-local)
    if (t == 255) blocksum[blockIdx.x] = sm[255];
}

// scan block totals in place; idle threads build the tail weight table in the
// LDS-friendly layout: Wtile[kk*64 + l] = (Wl2[k][j], Wr2[k][j]) with
// j = l>>3, k = (l&7) + kk*8  (kk in [0,16), l in [0,64))
__global__ void k_scan2(int* __restrict__ blocksum, int nb,
                        const float* __restrict__ Wl2, const float* __restrict__ Wr2,
                        float2* __restrict__ Wtile) {
    __shared__ int sm[256];
    int t = threadIdx.x;
    int v = (t < nb) ? blocksum[t] : 0;
    sm[t] = v;
    __syncthreads();
    #pragma unroll
    for (int off = 1; off < 256; off <<= 1) {
        int add = (t >= off) ? sm[t - off] : 0;
        __syncthreads();
        sm[t] += add;
        __syncthreads();
    }
    if (t < nb) blocksum[t] = sm[t] - v;
    #pragma unroll
    for (int i = 0; i < 4; ++i) {
        int idx = t + i * 256;
        int kk = idx >> 6, l = idx & 63;
        int j = l >> 3, sub = l & 7;
        int k = sub + kk * 8;
        Wtile[idx] = make_float2(Wl2[k * 8 + j], Wr2[k * 8 + j]);
    }
}

__global__ void k_part(const int* __restrict__ src, const int* __restrict__ dst,
                       const float* __restrict__ ea, const int* __restrict__ gofs,
                       const int* __restrict__ blocksum,
                       int2* __restrict__ tmp, int E, int CE, int NBK) {
    __shared__ int cur[256];
    int t = threadIdx.x;
    int c = blockIdx.x;
    if (t < NBK) cur[t] = gofs[t * 256 + c] + blocksum[t];
    __syncthreads();
    int lo = c * CE, hi = min(E, lo + CE);
    int len = hi - lo; if (len < 0) len = 0;
    int len4 = len & ~3;
    for (int o = t * 4; o < len4; o += 4096) {
        int e = lo + o;
        int4 s4 = *(const int4*)(src + e);
        int4 d4 = *(const int4*)(dst + e);
        float4 a4 = *(const float4*)(ea + e);
        int p0 = atomicAdd(&cur[d4.x >> 8], 1);
        int p1 = atomicAdd(&cur[d4.y >> 8], 1);
        int p2 = atomicAdd(&cur[d4.z >> 8], 1);
        int p3 = atomicAdd(&cur[d4.w >> 8], 1);
        tmp[p0] = make_int2(((d4.x & 255) << 24) | (s4.x << 4), __float_as_int(a4.x));
        tmp[p1] = make_int2(((d4.y & 255) << 24) | (s4.y << 4), __float_as_int(a4.y));
        tmp[p2] = make_int2(((d4.z & 255) << 24) | (s4.z << 4), __float_as_int(a4.z));
        tmp[p3] = make_int2(((d4.w & 255) << 24) | (s4.w << 4), __float_as_int(a4.w));
    }
    for (int o = len4 + t; o < len; o += 1024) {
        int e = lo + o;
        int d = dst[e];
        int pos = atomicAdd(&cur[d >> 8], 1);
        tmp[pos] = make_int2(((d & 255) << 24) | (src[e] << 4), __float_as_int(ea[e]));
    }
}

// fine sort within bucket (loop_ea removed: node kernels compute ea-sums inline)
__global__ void k_fsort(const int2* __restrict__ tmp, const int* __restrict__ gofs,
                        const int* __restrict__ blocksum,
                        int2* __restrict__ csr, int* __restrict__ row_ptr,
                        int N, int E, int NBK) {
    __shared__ int lcnt[256], lofs[256], lcur[256];
    int bkt = blockIdx.x;
    int t = threadIdx.x;
    int base = gofs[bkt * 256] + blocksum[bkt];
    int endv = (bkt == NBK - 1) ? E : (gofs[(bkt + 1) * 256] + blocksum[bkt + 1]);
    int cnt = endv - base;
    if (t < 256) lcnt[t] = 0;
    __syncthreads();
    for (int i = t; i < cnt; i += 1024) {
        int2 e2 = tmp[base + i];
        atomicAdd(&lcnt[(unsigned)e2.x >> 24], 1);
    }
    __syncthreads();
    int v = (t < 256) ? lcnt[t] : 0;
    if (t < 256) lofs[t] = v;
    __syncthreads();
    #pragma unroll
    for (int off = 1; off < 256; off <<= 1) {
        int add = (t >= off && t < 256) ? lofs[t - off] : 0;
        __syncthreads();
        if (t < 256) lofs[t] += add;
        __syncthreads();
    }
    if (t < 256) {
        int excl = lofs[t] - v;
        int nlo = bkt << 8;
        if (nlo + t < N) row_ptr[nlo + t] = base + excl;
        lcur[t] = base + excl;
    }
    __syncthreads();
    for (int i = t; i < cnt; i += 1024) {
        int2 e2 = tmp[base + i];
        int dl = (unsigned)e2.x >> 24;
        int pos = atomicAdd(&lcur[dl], 1);
        csr[pos] = make_int2(e2.x & 0x00FFFFFF, e2.y);
    }
    if (bkt == 0 && t == 0) row_ptr[N] = E;
}

// ---------------- layer 1 (fused with layer-2 linear) ----------------

// One wave per dst node, lane = 2 channels; node wave-uniform -> scalar s_loads.
// Simple x8/x4/x1 unroll (no manual pipelining: compiler schedules s_loads).
// ea-sum accumulated inline; self-loop processed LAST with eav = easum/deg.
// Tail weights staged in LDS once per block (entry barrier only).
__global__ void k_l1_node(const int2* __restrict__ csr, const int* __restrict__ row_ptr,
                          const float* __restrict__ x,
                          const float* __restrict__ Wl1, const float* __restrict__ bl1,
                          const float* __restrict__ Wr1, const float* __restrict__ br1,
                          const float* __restrict__ We1, const float* __restrict__ att1,
                          const float* __restrict__ bias1, const f32x2* __restrict__ Wtile,
                          const float* __restrict__ bl2, const float* __restrict__ br2,
                          float* __restrict__ xl2, float* __restrict__ xr2, int N) {
    __shared__ float hs[4][128];
    __shared__ f32x2 wlds[1024];
    int t = threadIdx.x;
    // preload the 8 KB weight tile (coalesced), barrier BEFORE divergent work
    #pragma unroll
    for (int i = 0; i < 4; ++i) wlds[t + i * 256] = Wtile[t + i * 256];
    __syncthreads();

    int wid = t >> 6;
    int lane = t & 63;
    int node = blockIdx.x * 4 + wid;
    if (node >= N) return;
    node = __builtin_amdgcn_readfirstlane(node);

    const f32x2* Wl1v = (const f32x2*)Wl1;
    f32x2 wl0 = Wl1v[lane],        wl1v = Wl1v[64 + lane];
    f32x2 wl2v = Wl1v[128 + lane], wl3v = Wl1v[192 + lane];
    f32x2 b2 = ((const f32x2*)bl1)[lane];
    float4 xv = *(const float4*)(x + (size_t)node * 4);
    const f32x2* Wr1v = (const f32x2*)Wr1;
    f32x2 rr = ((const f32x2*)br1)[lane];
    rr = pkfma(sp(xv.x), Wr1v[lane],       rr);
    rr = pkfma(sp(xv.y), Wr1v[64 + lane],  rr);
    rr = pkfma(sp(xv.z), Wr1v[128 + lane], rr);
    rr = pkfma(sp(xv.w), Wr1v[192 + lane], rr);
    f32x2 we2 = ((const f32x2*)We1)[lane];
    f32x2 at2 = ((const f32x2*)att1)[lane] * LOG2E;   // fold exp -> exp2
    const char* xb = (const char*)x;

    #define VL2(xs) pkfma(sp((xs).w), wl3v, pkfma(sp((xs).z), wl2v, \
                    pkfma(sp((xs).y), wl1v, pkfma(sp((xs).x), wl0, b2))))
    #define LOGIT(xs, ee, vl, aa) \
        f32x2 vl = VL2(xs); \
        float aa; \
        { f32x2 m_ = lrelu2(pkfma(sp(ee), we2, vl + rr)); \
          f32x2 q_ = m_ * at2; \
          float p_ = q_.x + q_.y; RED8(p_); aa = fexp2(p_); }

    int start = row_ptr[node];
    int deg   = row_ptr[node + 1] - start;
    const int2* crow = csr + start;

    float den = 0.0f;
    f32x2 acc = {0.0f, 0.0f};
    float easum = 0.0f;
    int k = 0;
    for (; k + 8 <= deg; k += 8) {
        int2 q0 = crow[k],     q1 = crow[k + 1], q2 = crow[k + 2], q3 = crow[k + 3];
        int2 q4 = crow[k + 4], q5 = crow[k + 5], q6 = crow[k + 6], q7 = crow[k + 7];
        float4 y0 = *(const float4*)(xb + (unsigned)q0.x);
        float4 y1 = *(const float4*)(xb + (unsigned)q1.x);
        float4 y2 = *(const float4*)(xb + (unsigned)q2.x);
        float4 y3 = *(const float4*)(xb + (unsigned)q3.x);
        float4 y4 = *(const float4*)(xb + (unsigned)q4.x);
        float4 y5 = *(const float4*)(xb + (unsigned)q5.x);
        float4 y6 = *(const float4*)(xb + (unsigned)q6.x);
        float4 y7 = *(const float4*)(xb + (unsigned)q7.x);
        float e0 = __int_as_float(q0.y), e1 = __int_as_float(q1.y);
        float e2 = __int_as_float(q2.y), e3 = __int_as_float(q3.y);
        float e4 = __int_as_float(q4.y), e5 = __int_as_float(q5.y);
        float e6 = __int_as_float(q6.y), e7 = __int_as_float(q7.y);
        easum += ((e0 + e1) + (e2 + e3)) + ((e4 + e5) + (e6 + e7));
        LOGIT(y0, e0, ul0, b0);
        LOGIT(y1, e1, ul1, b1);
        LOGIT(y2, e2, ul2, bb2);
        LOGIT(y3, e3, ul3, b3);
        LOGIT(y4, e4, ul4, b4);
        LOGIT(y5, e5, ul5, b5);
        LOGIT(y6, e6, ul6, b6);
        LOGIT(y7, e7, ul7, b7);
        den += ((b0 + b1) + (bb2 + b3)) + ((b4 + b5) + (b6 + b7));
        acc = pkfma(sp(b0), ul0, acc);
        acc = pkfma(sp(b1), ul1, acc);
        acc = pkfma(sp(bb2), ul2, acc);
        acc = pkfma(sp(b3), ul3, acc);
        acc = pkfma(sp(b4), ul4, acc);
        acc = pkfma(sp(b5), ul5, acc);
        acc = pkfma(sp(b6), ul6, acc);
        acc = pkfma(sp(b7), ul7, acc);
    }
    for (; k + 4 <= deg; k += 4) {
        int2 q0 = crow[k],     q1 = crow[k + 1];
        int2 q2 = crow[k + 2], q3 = crow[k + 3];
        float4 y0 = *(const float4*)(xb + (unsigned)q0.x);
        float4 y1 = *(const float4*)(xb + (unsigned)q1.x);
        float4 y2 = *(const float4*)(xb + (unsigned)q2.x);
        float4 y3 = *(const float4*)(xb + (unsigned)q3.x);
        float e0 = __int_as_float(q0.y), e1 = __int_as_float(q1.y);
        float e2 = __int_as_float(q2.y), e3 = __int_as_float(q3.y);
        easum += (e0 + e1) + (e2 + e3);
        LOGIT(y0, e0, vl0, a0);
        LOGIT(y1, e1, vl1, a1);
        LOGIT(y2, e2, vl2, a2);
        LOGIT(y3, e3, vl3, a3);
        den += (a0 + a1) + (a2 + a3);
        acc = pkfma(sp(a0), vl0, acc);
        acc = pkfma(sp(a1), vl1, acc);
        acc = pkfma(sp(a2), vl2, acc);
        acc = pkfma(sp(a3), vl3, acc);
    }
    for (; k < deg; ++k) {
        int2 pr = crow[k];
        float ee = __int_as_float(pr.y);
        float4 xs = *(const float4*)(xb + (unsigned)pr.x);
        easum += ee;
        LOGIT(xs, ee, vls2, aa);
        den += aa;
        acc = pkfma(sp(aa), vls2, acc);
    }
    // self-loop LAST: eav = mean of incoming ea (PyG fill_value='mean')
    {
        float eav = easum / fmaxf((float)deg, 1.0f);
        LOGIT(xv, eav, vls, a);
        den += a;
        acc = pkfma(sp(a), vls, acc);
    }
    #undef VL2
    #undef LOGIT
    f32x2 bia = ((const f32x2*)bias1)[lane];
    f32x2 o = pkfma(acc, sp(1.0f / den), bia);
    float o0 = elu1(o.x);
    float o1 = elu1(o.y);
    // per-wave LDS slice; same-wave DS ops are in-order -> no block barrier
    *(float2*)&hs[wid][lane * 2] = make_float2(o0, o1);

    // fused layer-2 linear: zero VMEM; lane (j=lane>>3, sub=lane&7) sums
    // k = sub + kk*8 for kk=0..15 (partition over subs covers all 128 k's)
    int j = lane >> 3, sub = lane & 7;
    f32x2 a2 = {0.0f, 0.0f};
    #pragma unroll
    for (int kk = 0; kk < 16; ++kk) {
        float hk = hs[wid][sub + kk * 8];
        a2 = pkfma(sp(hk), wlds[kk * 64 + lane], a2);
    }
    RED8(a2.x);
    RED8(a2.y);
    if (sub == 0) {
        xl2[(size_t)node * 8 + j] = a2.x + bl2[j];
        xr2[(size_t)node * 8 + j] = a2.y + br2[j];
    }
}

// ---------------- layer 2 ----------------

// 8 lanes per dst node, lane = edge within group. Per-lane local accumulation;
// deferred 10-value DPP reduce; self-loop handled post-reduction by lane 0.
__global__ void k_l2_node(const int2* __restrict__ csr, const int* __restrict__ row_ptr,
                          const float* __restrict__ xl2, const float* __restrict__ xr2,
                          const float* __restrict__ We2, const float* __restrict__ att2,
                          const float* __restrict__ bias2, float* __restrict__ h2, int N) {
    int t = blockIdx.x * blockDim.x + threadIdx.x;
    int node = t >> 3;
    int lane = t & 7;
    if (node >= N) return;
    float4 ra = *(const float4*)(xr2 + (size_t)node * 8);
    float4 rb = *(const float4*)(xr2 + (size_t)node * 8 + 4);
    f32x2 rv0 = {ra.x, ra.y}, rv1 = {ra.z, ra.w}, rv2 = {rb.x, rb.y}, rv3 = {rb.z, rb.w};
    f32x2 we0 = ((const f32x2*)We2)[0], we1 = ((const f32x2*)We2)[1];
    f32x2 we2v = ((const f32x2*)We2)[2], we3 = ((const f32x2*)We2)[3];
    f32x2 at0 = ((const f32x2*)att2)[0] * LOG2E, at1 = ((const f32x2*)att2)[1] * LOG2E;
    f32x2 at2v = ((const f32x2*)att2)[2] * LOG2E, at3 = ((const f32x2*)att2)[3] * LOG2E;
    const char* xlb = (const char*)xl2;
    int start = row_ptr[node], deg = row_ptr[node + 1] - start;
    float den = 0.0f, easum = 0.0f;
    f32x2 ac0 = {0,0}, ac1 = {0,0}, ac2 = {0,0}, ac3 = {0,0};
    for (int base = 0; base < deg; base += 8) {
        int e = base + lane;
        if (e < deg) {
            int2 pr = csr[start + e];
            const float* lp = (const float*)(xlb + 2u * (unsigned)pr.x);  // src*32 bytes
            float eav = __int_as_float(pr.y);
            easum += eav;
            float4 la = *(const float4*)lp;
            float4 lb = *(const float4*)(lp + 4);
            f32x2 l0 = {la.x, la.y}, l1 = {la.z, la.w};
            f32x2 l2 = {lb.x, lb.y}, l3 = {lb.z, lb.w};
            f32x2 ev = sp(eav);
            f32x2 q = lrelu2(pkfma(ev, we0, l0 + rv0)) * at0;
            q = pkfma(lrelu2(pkfma(ev, we1, l1 + rv1)), at1, q);
            q = pkfma(lrelu2(pkfma(ev, we2v, l2 + rv2)), at2v, q);
            q = pkfma(lrelu2(pkfma(ev, we3, l3 + rv3)), at3, q);
            float a = fexp2(q.x + q.y);
            den += a;
            f32x2 av = sp(a);
            ac0 = pkfma(av, l0, ac0);
            ac1 = pkfma(av, l1, ac1);
            ac2 = pkfma(av, l2, ac2);
            ac3 = pkfma(av, l3, ac3);
        }
    }
    // deferred reduction across the 8-lane group
    RED8(den);
    RED8(easum);
    float w0 = ac0.x, w1 = ac0.y, w2 = ac1.x, w3 = ac1.y;
    float w4 = ac2.x, w5 = ac2.y, w6 = ac3.x, w7 = ac3.y;
    RED8(w0); RED8(w1); RED8(w2); RED8(w3);
    RED8(w4); RED8(w5); RED8(w6); RED8(w7);
    if (lane == 0) {
        // self-loop: eav = mean of incoming ea
        float eav = easum / fmaxf((float)deg, 1.0f);
        const float* lp = xl2 + (size_t)node * 8;
        float4 la = *(const float4*)lp;
        float4 lb = *(const float4*)(lp + 4);
        f32x2 l0 = {la.x, la.y}, l1 = {la.z, la.w};
        f32x2 l2 = {lb.x, lb.y}, l3 = {lb.z, lb.w};
        f32x2 ev = sp(eav);
        f32x2 q = lrelu2(pkfma(ev, we0, l0 + rv0)) * at0;
        q = pkfma(lrelu2(pkfma(ev, we1, l1 + rv1)), at1, q);
        q = pkfma(lrelu2(pkfma(ev, we2v, l2 + rv2)), at2v, q);
        q = pkfma(lrelu2(pkfma(ev, we3, l3 + rv3)), at3, q);
        float a = fexp2(q.x + q.y);
        den += a;
        w0 = fmaf(a, la.x, w0); w1 = fmaf(a, la.y, w1);
        w2 = fmaf(a, la.z, w2); w3 = fmaf(a, la.w, w3);
        w4 = fmaf(a, lb.x, w4); w5 = fmaf(a, lb.y, w5);
        w6 = fmaf(a, lb.z, w6); w7 = fmaf(a, lb.w, w7);
        float inv = 1.0f / den;
        float o[8] = {w0, w1, w2, w3, w4, w5, w6, w7};
        #pragma unroll
        for (int cc = 0; cc < 8; ++cc) {
            float v = fmaf(o[cc], inv, bias2[cc]);
            o[cc] = elu1(v);
        }
        *(float4*)(h2 + (size_t)node * 8)     = make_float4(o[0], o[1], o[2], o[3]);
        *(float4*)(h2 + (size_t)node * 8 + 4) = make_float4(o[4], o[5], o[6], o[7]);
    }
}

// One block per graph; batch is sorted -> binary-search the segment.
__global__ void k_pool(const float* __restrict__ h2, const int* __restrict__ batch,
                       const float* __restrict__ W3, const float* __restrict__ b3,
                       float* __restrict__ out, int N) {
    int g = blockIdx.x;
    int lo = 0, hi = N;
    while (lo < hi) { int mid = (lo + hi) >> 1; if (batch[mid] < g) lo = mid + 1; else hi = mid; }
    int start = lo;
    int lo2 = start, hi2 = N;
    while (lo2 < hi2) { int mid = (lo2 + hi2) >> 1; if (batch[mid] < g + 1) lo2 = mid + 1; else hi2 = mid; }
    int end = lo2;
    int cnt = end - start;
    int t = threadIdx.x;
    int c = t & 7, rg = t >> 3;
    float s = 0.0f;
    for (int i = start + rg; i < end; i += 32) s += h2[(size_t)i * 8 + c];
    __shared__ float sm[256];
    sm[t] = s;
    __syncthreads();
    #pragma unroll
    for (int off = 16; off >= 1; off >>= 1) {
        if (rg < off) sm[t] += sm[t + off * 8];
        __syncthreads();
    }
    if (t == 0) {
        float inv = 1.0f / fmaxf((float)cnt, 1.0f);
        float acc = b3[0];
        #pragma unroll
        for (int cc = 0; cc < 8; ++cc) acc = fmaf(sm[cc] * inv, W3[cc], acc);
        out[g] = acc;
    }
}

extern "C" void kernel_launch(void* const* d_in, const int* in_sizes, int n_in,
                              void* d_out, int out_size, void* d_ws, size_t ws_size,
                              hipStream_t stream) {
    const float* x     = (const float*)d_in[0];
    const int*   ei    = (const int*)d_in[1];
    const float* ea    = (const float*)d_in[2];
    const int*   batch = (const int*)d_in[3];
    const float* Wl1 = (const float*)d_in[4];
    const float* bl1 = (const float*)d_in[5];
    const float* Wr1 = (const float*)d_in[6];
    const float* br1 = (const float*)d_in[7];
    const float* We1 = (const float*)d_in[8];
    const float* att1 = (const float*)d_in[9];
    const float* bias1 = (const float*)d_in[10];
    const float* Wl2 = (const float*)d_in[11];
    const float* bl2 = (const float*)d_in[12];
    const float* Wr2 = (const float*)d_in[13];
    const float* br2 = (const float*)d_in[14];
    const float* We2 = (const float*)d_in[15];
    const float* att2 = (const float*)d_in[16];
    const float* bias2 = (const float*)d_in[17];
    const float* W3 = (const float*)d_in[18];
    const float* b3 = (const float*)d_in[19];

    const int N  = in_sizes[0] / 4;
    const int E  = in_sizes[1] / 2;
    const int G  = out_size;
    const int* src = ei;
    const int* dst = ei + E;

    const int NBK = (N + 255) >> 8;                      // buckets of 256 nodes, <= 256
    const int NCH = 256;                                 // edge chunks
    const int CE  = (((E + NCH - 1) / NCH) + 3) & ~3;    // edges per chunk, x4-aligned
    const int L   = NBK * 256;                           // count-matrix length

    #define ALIGN4(v) (((v) + 3) & ~3)
    int* w = (int*)d_ws;
    int* gofs     = w; w += ALIGN4(L + 1);
    int* blocksum = w; w += 256;
    int* row_ptr  = w; w += ALIGN4(N + 1);
    float* xl2 = (float*)w; w += (size_t)N * 8;
    float* xr2 = (float*)w; w += (size_t)N * 8;
    float* h2  = (float*)w; w += (size_t)N * 8;
    float2* Wtile = (float2*)w; w += 2048;
    int2* tmp = (int2*)w; w += (size_t)E * 2;
    int2* csr = (int2*)w; w += (size_t)E * 2;
    #undef ALIGN4

    // CSR build: two-level counting sort (block-offset add folded into consumers)
    k_bcnt<<<NCH, 1024, 0, stream>>>(dst, gofs, E, CE, NBK);
    k_scan1<<<NBK, 256, 0, stream>>>(gofs, gofs, blocksum, L);
    k_scan2<<<1, 256, 0, stream>>>(blocksum, NBK, Wl2, Wr2, Wtile);
    k_part<<<NCH, 1024, 0, stream>>>(src, dst, ea, gofs, blocksum, tmp, E, CE, NBK);
    k_fsort<<<NBK, 1024, 0, stream>>>(tmp, gofs, blocksum, csr, row_ptr, N, E, NBK);

    // layer 1 (+ fused layer-2 linear; h1 never touches HBM)
    k_l1_node<<<(N + 3) / 4, 256, 0, stream>>>(csr, row_ptr, x,
                                               Wl1, bl1, Wr1, br1, We1, att1, bias1,
                                               (const f32x2*)Wtile, bl2, br2, xl2, xr2, N);
    // layer 2
    k_l2_node<<<((size_t)N * 8 + 255) / 256, 256, 0, stream>>>(csr, row_ptr, xl2, xr2,
                                                               We2, att2, bias2, h2, N);
    // pool + final linear
    k_pool<<<G, 256, 0, stream>>>(h2, batch, W3, b3, (float*)d_out, N);
}